// Round 1
// baseline (16184.914 us; speedup 1.0000x reference)
//
#include <hip/hip_runtime.h>
#include <hip/hip_bf16.h>

#define HH 128     // hidden
#define G4 512     // 4*H
#define TT 256     // encoder timesteps
#define BB 512     // batch
#define NPRED 50   // decoder steps

typedef unsigned short u16;
typedef unsigned int u32;

__device__ __forceinline__ float sigm(float x) { return 1.0f / (1.0f + __expf(-x)); }
__device__ __forceinline__ float tanhf_(float x) { return 1.0f - 2.0f / (__expf(2.0f * x) + 1.0f); }
__device__ __forceinline__ float bf2f(u16 u) { return __uint_as_float(((u32)u) << 16); }
__device__ __forceinline__ u16 f2bf(float f) {
    u32 x = __float_as_uint(f);
    u32 r = (x + 0x7fffu + ((x >> 16) & 1u)) >> 16;   // RTNE
    return (u16)r;
}

// ---------------------------------------------------------------------------
// Encoder layer 0: input (B,T,4). whh row in f32 VGPRs, wih row (4) in VGPRs.
// Block = 512 thr (8 waves), owns 2 batch elements. Grid = 256.
// ---------------------------------------------------------------------------
__global__ void __launch_bounds__(512, 2) k_scan0(
    const float* __restrict__ x, const float* __restrict__ wih,
    const float* __restrict__ whh, const float* __restrict__ bih,
    const float* __restrict__ bhh, u16* __restrict__ ys,
    float* __restrict__ hst, float* __restrict__ cst)
{
    const int tid = threadIdx.x;
    const int j = tid;
    const int b0 = blockIdx.x * 2;
    __shared__ __align__(16) float h_s[2][HH];
    __shared__ __align__(16) float z_s[2][G4];
    __shared__ __align__(16) float x_s[2][4];

    float wr[HH];
    const float* wrow = whh + (size_t)j * HH;
#pragma unroll
    for (int k4 = 0; k4 < HH / 4; k4++) {
        float4 v = reinterpret_cast<const float4*>(wrow)[k4];
        wr[4 * k4] = v.x; wr[4 * k4 + 1] = v.y; wr[4 * k4 + 2] = v.z; wr[4 * k4 + 3] = v.w;
    }
    const float wi0 = wih[j * 4], wi1 = wih[j * 4 + 1], wi2 = wih[j * 4 + 2], wi3 = wih[j * 4 + 3];
    const float bias = bih[j] + bhh[j];
    float creg = 0.f;

    if (tid < 2 * HH) h_s[tid >> 7][tid & 127] = 0.f;
    if (tid < 8) x_s[tid >> 2][tid & 3] = x[(size_t)(b0 + (tid >> 2)) * TT * 4 + (tid & 3)];
    __syncthreads();

    for (int t = 0; t < TT; t++) {
#pragma unroll
        for (int b = 0; b < 2; b++) {
            float acc = bias + wi0 * x_s[b][0] + wi1 * x_s[b][1] + wi2 * x_s[b][2] + wi3 * x_s[b][3];
#pragma unroll
            for (int k4 = 0; k4 < HH / 4; k4++) {
                float4 hv = reinterpret_cast<const float4*>(h_s[b])[k4];
                acc += wr[4 * k4] * hv.x + wr[4 * k4 + 1] * hv.y + wr[4 * k4 + 2] * hv.z + wr[4 * k4 + 3] * hv.w;
            }
            z_s[b][j] = acc;
        }
        __syncthreads();
        if (tid < 2 * HH) {
            const int b = tid >> 7, jh = tid & 127;
            float zi = z_s[b][jh], zf = z_s[b][HH + jh], zg = z_s[b][2 * HH + jh], zo = z_s[b][3 * HH + jh];
            float c = sigm(zf) * creg + sigm(zi) * tanhf_(zg);
            float h = sigm(zo) * tanhf_(c);
            creg = c;
            h_s[b][jh] = h;
            ys[((size_t)(b0 + b) * TT + t) * HH + jh] = f2bf(h);
        } else if (tid >= 504) {
            if (t + 1 < TT) {
                int q = tid - 504; // 0..7
                x_s[q >> 2][q & 3] = x[(size_t)(b0 + (q >> 2)) * TT * 4 + (size_t)(t + 1) * 4 + (q & 3)];
            }
        }
        __syncthreads();
    }
    if (tid < 2 * HH) {
        const int b = tid >> 7, jh = tid & 127;
        hst[(size_t)(b0 + b) * HH + jh] = h_s[b][jh];
        cst[(size_t)(b0 + b) * HH + jh] = creg;
    }
}

// ---------------------------------------------------------------------------
// Encoder layers 1,2: input sequence from ys (bf16, in place). whh f32 VGPRs,
// wih bf16-packed VGPRs. Block = 512 thr, 2 batch el. Grid = 256.
// ---------------------------------------------------------------------------
__global__ void __launch_bounds__(512, 2) k_scanL(
    const float* __restrict__ wih, const float* __restrict__ whh,
    const float* __restrict__ bih, const float* __restrict__ bhh,
    u16* __restrict__ ys, int write_ys,
    float* __restrict__ hst, float* __restrict__ cst)
{
    const int tid = threadIdx.x;
    const int j = tid;
    const int b0 = blockIdx.x * 2;
    __shared__ __align__(16) float h_s[2][HH];
    __shared__ __align__(16) float y_s[2][HH];
    __shared__ __align__(16) float z_s[2][G4];

    float wr[HH];
#pragma unroll
    for (int k4 = 0; k4 < HH / 4; k4++) {
        float4 v = reinterpret_cast<const float4*>(whh + (size_t)j * HH)[k4];
        wr[4 * k4] = v.x; wr[4 * k4 + 1] = v.y; wr[4 * k4 + 2] = v.z; wr[4 * k4 + 3] = v.w;
    }
    u32 wp[HH / 2];
#pragma unroll
    for (int k2 = 0; k2 < HH / 2; k2++) {
        float2 v = reinterpret_cast<const float2*>(wih + (size_t)j * HH)[k2];
        wp[k2] = (u32)f2bf(v.x) | ((u32)f2bf(v.y) << 16);
    }
    const float bias = bih[j] + bhh[j];
    float creg = 0.f;

    if (tid < 2 * HH) {
        const int b = tid >> 7, jh = tid & 127;
        h_s[b][jh] = 0.f;
        y_s[b][jh] = bf2f(ys[((size_t)(b0 + b) * TT) * HH + jh]);
    }
    __syncthreads();

    for (int t = 0; t < TT; t++) {
#pragma unroll
        for (int b = 0; b < 2; b++) {
            float acc = bias;
#pragma unroll
            for (int k4 = 0; k4 < HH / 4; k4++) {
                float4 hv = reinterpret_cast<const float4*>(h_s[b])[k4];
                acc += wr[4 * k4] * hv.x + wr[4 * k4 + 1] * hv.y + wr[4 * k4 + 2] * hv.z + wr[4 * k4 + 3] * hv.w;
                float4 yv = reinterpret_cast<const float4*>(y_s[b])[k4];
                u32 p0 = wp[2 * k4], p1 = wp[2 * k4 + 1];
                acc += __uint_as_float(p0 << 16) * yv.x + __uint_as_float(p0 & 0xffff0000u) * yv.y
                     + __uint_as_float(p1 << 16) * yv.z + __uint_as_float(p1 & 0xffff0000u) * yv.w;
            }
            z_s[b][j] = acc;
        }
        __syncthreads();
        if (tid < 2 * HH) {
            const int b = tid >> 7, jh = tid & 127;
            float zi = z_s[b][jh], zf = z_s[b][HH + jh], zg = z_s[b][2 * HH + jh], zo = z_s[b][3 * HH + jh];
            float c = sigm(zf) * creg + sigm(zi) * tanhf_(zg);
            float h = sigm(zo) * tanhf_(c);
            creg = c;
            h_s[b][jh] = h;
            if (write_ys) ys[((size_t)(b0 + b) * TT + t) * HH + jh] = f2bf(h);
            if (t + 1 < TT) y_s[b][jh] = bf2f(ys[((size_t)(b0 + b) * TT + (t + 1)) * HH + jh]);
        }
        __syncthreads();
    }
    if (tid < 2 * HH) {
        const int b = tid >> 7, jh = tid & 127;
        hst[(size_t)(b0 + b) * HH + jh] = h_s[b][jh];
        cst[(size_t)(b0 + b) * HH + jh] = creg;
    }
}

// ---------------------------------------------------------------------------
// Decoder: 50 steps x 3 layers, weights streamed from L2 (f32).
// Block = 512 thr, 4 batch el. Grid = 128. Thread j owns row j of every
// matrix; thread (bb,jh) owns the (b, h-element) cell states.
// ---------------------------------------------------------------------------
__global__ void __launch_bounds__(512, 2) k_decode(
    const float* __restrict__ x,
    const float* __restrict__ w0i, const float* __restrict__ w0h,
    const float* __restrict__ b0i, const float* __restrict__ b0h,
    const float* __restrict__ w1i, const float* __restrict__ w1h,
    const float* __restrict__ b1i, const float* __restrict__ b1h,
    const float* __restrict__ w2i, const float* __restrict__ w2h,
    const float* __restrict__ b2i, const float* __restrict__ b2h,
    const float* __restrict__ fcw, const float* __restrict__ fcb,
    const float* __restrict__ hst, const float* __restrict__ cst,
    float* __restrict__ out)
{
    const int tid = threadIdx.x;
    const int j = tid;
    const int b0 = blockIdx.x * 4;
    __shared__ __align__(16) float h_s[3][4][HH];
    __shared__ __align__(16) float z_s[4][G4];
    __shared__ __align__(16) float in0_s[4][4];
    __shared__ __align__(16) float fcw_s[HH];

    const int bb = tid >> 7, jh = tid & 127;
    float c0 = cst[((size_t)0 * BB + b0 + bb) * HH + jh];
    float c1 = cst[((size_t)1 * BB + b0 + bb) * HH + jh];
    float c2 = cst[((size_t)2 * BB + b0 + bb) * HH + jh];
    h_s[0][bb][jh] = hst[((size_t)0 * BB + b0 + bb) * HH + jh];
    h_s[1][bb][jh] = hst[((size_t)1 * BB + b0 + bb) * HH + jh];
    h_s[2][bb][jh] = hst[((size_t)2 * BB + b0 + bb) * HH + jh];
    if (tid < HH) fcw_s[tid] = fcw[tid];
    if (tid < 16) in0_s[tid >> 2][tid & 3] = x[(size_t)(b0 + (tid >> 2)) * TT * 4 + (size_t)(TT - 1) * 4 + (tid & 3)];

    const float bs0 = b0i[j] + b0h[j], bs1 = b1i[j] + b1h[j], bs2 = b2i[j] + b2h[j];
    const float wi00 = w0i[j * 4], wi01 = w0i[j * 4 + 1], wi02 = w0i[j * 4 + 2], wi03 = w0i[j * 4 + 3];
    const float fcbv = fcb[0];
    __syncthreads();

    for (int s = 0; s < NPRED; s++) {
        // ----- layer 0 -----
        {
            float a[4];
#pragma unroll
            for (int b = 0; b < 4; b++)
                a[b] = bs0 + wi00 * in0_s[b][0] + wi01 * in0_s[b][1] + wi02 * in0_s[b][2] + wi03 * in0_s[b][3];
            const float4* wrh = reinterpret_cast<const float4*>(w0h + (size_t)j * HH);
#pragma unroll
            for (int k4 = 0; k4 < HH / 4; k4++) {
                float4 w = wrh[k4];
#pragma unroll
                for (int b = 0; b < 4; b++) {
                    float4 hv = reinterpret_cast<const float4*>(h_s[0][b])[k4];
                    a[b] += w.x * hv.x + w.y * hv.y + w.z * hv.z + w.w * hv.w;
                }
            }
#pragma unroll
            for (int b = 0; b < 4; b++) z_s[b][j] = a[b];
        }
        __syncthreads();
        {
            float zi = z_s[bb][jh], zf = z_s[bb][HH + jh], zg = z_s[bb][2 * HH + jh], zo = z_s[bb][3 * HH + jh];
            c0 = sigm(zf) * c0 + sigm(zi) * tanhf_(zg);
            h_s[0][bb][jh] = sigm(zo) * tanhf_(c0);
        }
        __syncthreads();
        // ----- layer 1 -----
        {
            float a[4] = { bs1, bs1, bs1, bs1 };
            const float4* wri = reinterpret_cast<const float4*>(w1i + (size_t)j * HH);
            const float4* wrh = reinterpret_cast<const float4*>(w1h + (size_t)j * HH);
#pragma unroll
            for (int k4 = 0; k4 < HH / 4; k4++) {
                float4 wiv = wri[k4];
                float4 whv = wrh[k4];
#pragma unroll
                for (int b = 0; b < 4; b++) {
                    float4 xv = reinterpret_cast<const float4*>(h_s[0][b])[k4];
                    float4 hv = reinterpret_cast<const float4*>(h_s[1][b])[k4];
                    a[b] += wiv.x * xv.x + wiv.y * xv.y + wiv.z * xv.z + wiv.w * xv.w
                          + whv.x * hv.x + whv.y * hv.y + whv.z * hv.z + whv.w * hv.w;
                }
            }
#pragma unroll
            for (int b = 0; b < 4; b++) z_s[b][j] = a[b];
        }
        __syncthreads();
        {
            float zi = z_s[bb][jh], zf = z_s[bb][HH + jh], zg = z_s[bb][2 * HH + jh], zo = z_s[bb][3 * HH + jh];
            c1 = sigm(zf) * c1 + sigm(zi) * tanhf_(zg);
            h_s[1][bb][jh] = sigm(zo) * tanhf_(c1);
        }
        __syncthreads();
        // ----- layer 2 -----
        {
            float a[4] = { bs2, bs2, bs2, bs2 };
            const float4* wri = reinterpret_cast<const float4*>(w2i + (size_t)j * HH);
            const float4* wrh = reinterpret_cast<const float4*>(w2h + (size_t)j * HH);
#pragma unroll
            for (int k4 = 0; k4 < HH / 4; k4++) {
                float4 wiv = wri[k4];
                float4 whv = wrh[k4];
#pragma unroll
                for (int b = 0; b < 4; b++) {
                    float4 xv = reinterpret_cast<const float4*>(h_s[1][b])[k4];
                    float4 hv = reinterpret_cast<const float4*>(h_s[2][b])[k4];
                    a[b] += wiv.x * xv.x + wiv.y * xv.y + wiv.z * xv.z + wiv.w * xv.w
                          + whv.x * hv.x + whv.y * hv.y + whv.z * hv.z + whv.w * hv.w;
                }
            }
#pragma unroll
            for (int b = 0; b < 4; b++) z_s[b][j] = a[b];
        }
        __syncthreads();
        {
            float zi = z_s[bb][jh], zf = z_s[bb][HH + jh], zg = z_s[bb][2 * HH + jh], zo = z_s[bb][3 * HH + jh];
            c2 = sigm(zf) * c2 + sigm(zi) * tanhf_(zg);
            h_s[2][bb][jh] = sigm(zo) * tanhf_(c2);
        }
        __syncthreads();
        // ----- fc + feedback -----
        if (tid < 256) {
            const int w = tid >> 6, lane = tid & 63;
            float p = h_s[2][w][lane] * fcw_s[lane] + h_s[2][w][lane + 64] * fcw_s[lane + 64];
#pragma unroll
            for (int off = 32; off > 0; off >>= 1) p += __shfl_down(p, off);
            if (lane == 0) {
                float pr = p + fcbv;
                out[(size_t)(b0 + w) * NPRED + s] = pr;
                in0_s[w][0] = pr;
            }
        } else if (tid < 272) {
            int q = tid - 256;            // 0..15
            int b = q >> 2, k = q & 3;
            if (k > 0) in0_s[b][k] = 0.f; // zeros_feat
        }
        __syncthreads();
    }
}

extern "C" void kernel_launch(void* const* d_in, const int* in_sizes, int n_in,
                              void* d_out, int out_size, void* d_ws, size_t ws_size,
                              hipStream_t stream)
{
    const float* x = (const float*)d_in[0];
    // encoder params at 1 + 4l, decoder at 13 + 4l
    const float* e0_wih = (const float*)d_in[1];
    const float* e0_whh = (const float*)d_in[2];
    const float* e0_bih = (const float*)d_in[3];
    const float* e0_bhh = (const float*)d_in[4];
    const float* e1_wih = (const float*)d_in[5];
    const float* e1_whh = (const float*)d_in[6];
    const float* e1_bih = (const float*)d_in[7];
    const float* e1_bhh = (const float*)d_in[8];
    const float* e2_wih = (const float*)d_in[9];
    const float* e2_whh = (const float*)d_in[10];
    const float* e2_bih = (const float*)d_in[11];
    const float* e2_bhh = (const float*)d_in[12];
    const float* fc_w = (const float*)d_in[25];
    const float* fc_b = (const float*)d_in[26];

    // workspace layout
    u16* ys = (u16*)d_ws;                                   // B*T*H bf16 = 33.5 MB
    size_t ys_bytes = (size_t)BB * TT * HH * sizeof(u16);
    float* hst = (float*)((char*)d_ws + ys_bytes);          // 3*B*H f32
    float* cst = hst + (size_t)3 * BB * HH;                 // 3*B*H f32
    const size_t BH = (size_t)BB * HH;

    k_scan0<<<dim3(256), dim3(512), 0, stream>>>(x, e0_wih, e0_whh, e0_bih, e0_bhh,
                                                 ys, hst, cst);
    k_scanL<<<dim3(256), dim3(512), 0, stream>>>(e1_wih, e1_whh, e1_bih, e1_bhh,
                                                 ys, 1, hst + BH, cst + BH);
    k_scanL<<<dim3(256), dim3(512), 0, stream>>>(e2_wih, e2_whh, e2_bih, e2_bhh,
                                                 ys, 0, hst + 2 * BH, cst + 2 * BH);
    k_decode<<<dim3(128), dim3(512), 0, stream>>>(
        x,
        (const float*)d_in[13], (const float*)d_in[14], (const float*)d_in[15], (const float*)d_in[16],
        (const float*)d_in[17], (const float*)d_in[18], (const float*)d_in[19], (const float*)d_in[20],
        (const float*)d_in[21], (const float*)d_in[22], (const float*)d_in[23], (const float*)d_in[24],
        fc_w, fc_b, hst, cst, (float*)d_out);
}

// Round 3
// 6189.661 us; speedup vs baseline: 2.6148x; 2.6148x over previous
//
#include <hip/hip_runtime.h>
#include <hip/hip_bf16.h>

#define HH 128     // hidden
#define G4 512     // 4*H
#define TT 256     // encoder timesteps
#define BB 512     // batch
#define NPRED 50   // decoder steps

typedef unsigned short u16;
typedef unsigned int u32;

__device__ __forceinline__ float sigm(float x) { return 1.0f / (1.0f + __expf(-x)); }
__device__ __forceinline__ float tanhf_(float x) { return 1.0f - 2.0f / (__expf(2.0f * x) + 1.0f); }
__device__ __forceinline__ float bf2f(u16 u) { return __uint_as_float(((u32)u) << 16); }
__device__ __forceinline__ u16 f2bf(float f) {
    u32 x = __float_as_uint(f);
    u32 r = (x + 0x7fffu + ((x >> 16) & 1u)) >> 16;   // RTNE
    return (u16)r;
}

// ---------------------------------------------------------------------------
// Encoder layer 0. 512 threads, 2 batch el/block, grid 256 (1 block/CU).
// __launch_bounds__(512, 1): VGPR cap 256 (2 waves/SIMD) — thread j holds the
// FULL whh row (128 f32 = 128 VGPRs) with no spill. Round 1 used (512,2),
// capping at 128 VGPRs and spilling ~70 regs -> 18 GB scratch reads/dispatch.
// h_s reads are wave-uniform (broadcast, conflict-free).
// ---------------------------------------------------------------------------
__global__ void __launch_bounds__(512, 1) k_scan0(
    const float* __restrict__ x, const float* __restrict__ wih,
    const float* __restrict__ whh, const float* __restrict__ bih,
    const float* __restrict__ bhh, u16* __restrict__ ys,
    float* __restrict__ hst, float* __restrict__ cst)
{
    const int tid = threadIdx.x;
    const int j = tid;
    const int b0 = blockIdx.x * 2;
    __shared__ __align__(16) float h_s[2][HH];
    __shared__ __align__(16) float z_s[2][G4];
    __shared__ float x_s[2][4];

    float wr[HH];
    {
        const float4* wrow = reinterpret_cast<const float4*>(whh + (size_t)j * HH);
#pragma unroll
        for (int k4 = 0; k4 < HH / 4; k4++) {
            float4 v = wrow[k4];
            wr[4 * k4] = v.x; wr[4 * k4 + 1] = v.y; wr[4 * k4 + 2] = v.z; wr[4 * k4 + 3] = v.w;
        }
    }
    const float wi0 = wih[j * 4], wi1 = wih[j * 4 + 1], wi2 = wih[j * 4 + 2], wi3 = wih[j * 4 + 3];
    const float bias = bih[j] + bhh[j];
    const int bb = tid >> 7, jh = tid & 127;   // eltwise roles (tid < 256)
    float creg = 0.f;

    if (tid < 256) h_s[bb][jh] = 0.f;
    if (tid < 8) x_s[tid >> 2][tid & 3] = x[(size_t)(b0 + (tid >> 2)) * TT * 4 + (tid & 3)];
    __syncthreads();

    for (int t = 0; t < TT; t++) {
        // issue next-step x load early; written to LDS after the barrier
        float xnext = 0.f;
        if (tid < 8 && t + 1 < TT)
            xnext = x[(size_t)(b0 + (tid >> 2)) * TT * 4 + (size_t)(t + 1) * 4 + (tid & 3)];

        float a0 = bias + wi0 * x_s[0][0] + wi1 * x_s[0][1] + wi2 * x_s[0][2] + wi3 * x_s[0][3];
        float a1 = bias + wi0 * x_s[1][0] + wi1 * x_s[1][1] + wi2 * x_s[1][2] + wi3 * x_s[1][3];
#pragma unroll
        for (int k4 = 0; k4 < HH / 4; k4++) {
            float4 h0 = reinterpret_cast<const float4*>(h_s[0])[k4];
            a0 += wr[4 * k4] * h0.x + wr[4 * k4 + 1] * h0.y + wr[4 * k4 + 2] * h0.z + wr[4 * k4 + 3] * h0.w;
            float4 h1 = reinterpret_cast<const float4*>(h_s[1])[k4];
            a1 += wr[4 * k4] * h1.x + wr[4 * k4 + 1] * h1.y + wr[4 * k4 + 2] * h1.z + wr[4 * k4 + 3] * h1.w;
        }
        z_s[0][j] = a0;
        z_s[1][j] = a1;
        __syncthreads();

        if (tid < 256) {
            float zi = z_s[bb][jh], zf = z_s[bb][HH + jh], zg = z_s[bb][2 * HH + jh], zo = z_s[bb][3 * HH + jh];
            float c = sigm(zf) * creg + sigm(zi) * tanhf_(zg);
            float h = sigm(zo) * tanhf_(c);
            creg = c;
            h_s[bb][jh] = h;
            ys[((size_t)(b0 + bb) * TT + t) * HH + jh] = f2bf(h);
        }
        if (tid < 8 && t + 1 < TT) x_s[tid >> 2][tid & 3] = xnext;
        __syncthreads();
    }
    if (tid < 256) {
        hst[(size_t)(b0 + bb) * HH + jh] = h_s[bb][jh];
        cst[(size_t)(b0 + bb) * HH + jh] = creg;
    }
}

// ---------------------------------------------------------------------------
// Encoder layers 1,2. Thread j: whh row f32 (128 VGPRs) + wih row bf16-packed
// (64 VGPRs). ~220 VGPRs total < 256 cap — no spill. Input seq from ys (bf16),
// updated in place (each block owns its 2 batch rows across both layers).
// ---------------------------------------------------------------------------
__global__ void __launch_bounds__(512, 1) k_scanL(
    const float* __restrict__ wih, const float* __restrict__ whh,
    const float* __restrict__ bih, const float* __restrict__ bhh,
    u16* __restrict__ ys, int write_ys,
    float* __restrict__ hst, float* __restrict__ cst)
{
    const int tid = threadIdx.x;
    const int j = tid;
    const int b0 = blockIdx.x * 2;
    __shared__ __align__(16) float h_s[2][HH];
    __shared__ __align__(16) float y_s[2][HH];
    __shared__ __align__(16) float z_s[2][G4];

    float wr[HH];
    {
        const float4* wrow = reinterpret_cast<const float4*>(whh + (size_t)j * HH);
#pragma unroll
        for (int k4 = 0; k4 < HH / 4; k4++) {
            float4 v = wrow[k4];
            wr[4 * k4] = v.x; wr[4 * k4 + 1] = v.y; wr[4 * k4 + 2] = v.z; wr[4 * k4 + 3] = v.w;
        }
    }
    u32 wp[HH / 2];
    {
        const float2* wrow = reinterpret_cast<const float2*>(wih + (size_t)j * HH);
#pragma unroll
        for (int k2 = 0; k2 < HH / 2; k2++) {
            float2 v = wrow[k2];
            wp[k2] = (u32)f2bf(v.x) | ((u32)f2bf(v.y) << 16);
        }
    }
    const float bias = bih[j] + bhh[j];
    const int bb = tid >> 7, jh = tid & 127;
    float creg = 0.f;

    if (tid < 256) {
        h_s[bb][jh] = 0.f;
        y_s[bb][jh] = bf2f(ys[((size_t)(b0 + bb) * TT) * HH + jh]);
    }
    __syncthreads();

    for (int t = 0; t < TT; t++) {
        // issue next-step y load early (latency hidden under the FMA loop)
        u16 ynext = 0;
        if (tid < 256 && t + 1 < TT)
            ynext = ys[((size_t)(b0 + bb) * TT + (t + 1)) * HH + jh];

        float a0 = bias, a1 = bias;
#pragma unroll
        for (int k4 = 0; k4 < HH / 4; k4++) {
            float4 h0 = reinterpret_cast<const float4*>(h_s[0])[k4];
            a0 += wr[4 * k4] * h0.x + wr[4 * k4 + 1] * h0.y + wr[4 * k4 + 2] * h0.z + wr[4 * k4 + 3] * h0.w;
            float4 h1 = reinterpret_cast<const float4*>(h_s[1])[k4];
            a1 += wr[4 * k4] * h1.x + wr[4 * k4 + 1] * h1.y + wr[4 * k4 + 2] * h1.z + wr[4 * k4 + 3] * h1.w;
            u32 p0 = wp[2 * k4], p1 = wp[2 * k4 + 1];
            float w0 = __uint_as_float(p0 << 16), w1 = __uint_as_float(p0 & 0xffff0000u);
            float w2 = __uint_as_float(p1 << 16), w3 = __uint_as_float(p1 & 0xffff0000u);
            float4 q0 = reinterpret_cast<const float4*>(y_s[0])[k4];
            a0 += w0 * q0.x + w1 * q0.y + w2 * q0.z + w3 * q0.w;
            float4 q1 = reinterpret_cast<const float4*>(y_s[1])[k4];
            a1 += w0 * q1.x + w1 * q1.y + w2 * q1.z + w3 * q1.w;
        }
        z_s[0][j] = a0;
        z_s[1][j] = a1;
        __syncthreads();

        if (tid < 256) {
            float zi = z_s[bb][jh], zf = z_s[bb][HH + jh], zg = z_s[bb][2 * HH + jh], zo = z_s[bb][3 * HH + jh];
            float c = sigm(zf) * creg + sigm(zi) * tanhf_(zg);
            float h = sigm(zo) * tanhf_(c);
            creg = c;
            h_s[bb][jh] = h;
            if (write_ys) ys[((size_t)(b0 + bb) * TT + t) * HH + jh] = f2bf(h);
            if (t + 1 < TT) y_s[bb][jh] = bf2f(ynext);
        }
        __syncthreads();
    }
    if (tid < 256) {
        hst[(size_t)(b0 + bb) * HH + jh] = h_s[bb][jh];
        cst[(size_t)(b0 + bb) * HH + jh] = creg;
    }
}

// ---------------------------------------------------------------------------
// Decoder: 50 steps x 3 layers, weights streamed from L2 (f32).
// Block = 512 thr, 4 batch el. Grid = 128. (unchanged this round; next-round
// target: bf16 weight stream to halve L2 traffic)
// ---------------------------------------------------------------------------
__global__ void __launch_bounds__(512) k_decode(
    const float* __restrict__ x,
    const float* __restrict__ w0i, const float* __restrict__ w0h,
    const float* __restrict__ b0i, const float* __restrict__ b0h,
    const float* __restrict__ w1i, const float* __restrict__ w1h,
    const float* __restrict__ b1i, const float* __restrict__ b1h,
    const float* __restrict__ w2i, const float* __restrict__ w2h,
    const float* __restrict__ b2i, const float* __restrict__ b2h,
    const float* __restrict__ fcw, const float* __restrict__ fcb,
    const float* __restrict__ hst, const float* __restrict__ cst,
    float* __restrict__ out)
{
    const int tid = threadIdx.x;
    const int j = tid;
    const int b0 = blockIdx.x * 4;
    __shared__ __align__(16) float h_s[3][4][HH];
    __shared__ __align__(16) float z_s[4][G4];
    __shared__ __align__(16) float in0_s[4][4];
    __shared__ __align__(16) float fcw_s[HH];

    const int bb = tid >> 7, jh = tid & 127;
    float c0 = cst[((size_t)0 * BB + b0 + bb) * HH + jh];
    float c1 = cst[((size_t)1 * BB + b0 + bb) * HH + jh];
    float c2 = cst[((size_t)2 * BB + b0 + bb) * HH + jh];
    h_s[0][bb][jh] = hst[((size_t)0 * BB + b0 + bb) * HH + jh];
    h_s[1][bb][jh] = hst[((size_t)1 * BB + b0 + bb) * HH + jh];
    h_s[2][bb][jh] = hst[((size_t)2 * BB + b0 + bb) * HH + jh];
    if (tid < HH) fcw_s[tid] = fcw[tid];
    if (tid < 16) in0_s[tid >> 2][tid & 3] = x[(size_t)(b0 + (tid >> 2)) * TT * 4 + (size_t)(TT - 1) * 4 + (tid & 3)];

    const float bs0 = b0i[j] + b0h[j], bs1 = b1i[j] + b1h[j], bs2 = b2i[j] + b2h[j];
    const float wi00 = w0i[j * 4], wi01 = w0i[j * 4 + 1], wi02 = w0i[j * 4 + 2], wi03 = w0i[j * 4 + 3];
    const float fcbv = fcb[0];
    __syncthreads();

    for (int s = 0; s < NPRED; s++) {
        // ----- layer 0 -----
        {
            float a[4];
#pragma unroll
            for (int b = 0; b < 4; b++)
                a[b] = bs0 + wi00 * in0_s[b][0] + wi01 * in0_s[b][1] + wi02 * in0_s[b][2] + wi03 * in0_s[b][3];
            const float4* wrh = reinterpret_cast<const float4*>(w0h + (size_t)j * HH);
#pragma unroll
            for (int k4 = 0; k4 < HH / 4; k4++) {
                float4 w = wrh[k4];
#pragma unroll
                for (int b = 0; b < 4; b++) {
                    float4 hv = reinterpret_cast<const float4*>(h_s[0][b])[k4];
                    a[b] += w.x * hv.x + w.y * hv.y + w.z * hv.z + w.w * hv.w;
                }
            }
#pragma unroll
            for (int b = 0; b < 4; b++) z_s[b][j] = a[b];
        }
        __syncthreads();
        {
            float zi = z_s[bb][jh], zf = z_s[bb][HH + jh], zg = z_s[bb][2 * HH + jh], zo = z_s[bb][3 * HH + jh];
            c0 = sigm(zf) * c0 + sigm(zi) * tanhf_(zg);
            h_s[0][bb][jh] = sigm(zo) * tanhf_(c0);
        }
        __syncthreads();
        // ----- layer 1 -----
        {
            float a[4] = { bs1, bs1, bs1, bs1 };
            const float4* wri = reinterpret_cast<const float4*>(w1i + (size_t)j * HH);
            const float4* wrh = reinterpret_cast<const float4*>(w1h + (size_t)j * HH);
#pragma unroll
            for (int k4 = 0; k4 < HH / 4; k4++) {
                float4 wiv = wri[k4];
                float4 whv = wrh[k4];
#pragma unroll
                for (int b = 0; b < 4; b++) {
                    float4 xv = reinterpret_cast<const float4*>(h_s[0][b])[k4];
                    float4 hv = reinterpret_cast<const float4*>(h_s[1][b])[k4];
                    a[b] += wiv.x * xv.x + wiv.y * xv.y + wiv.z * xv.z + wiv.w * xv.w
                          + whv.x * hv.x + whv.y * hv.y + whv.z * hv.z + whv.w * hv.w;
                }
            }
#pragma unroll
            for (int b = 0; b < 4; b++) z_s[b][j] = a[b];
        }
        __syncthreads();
        {
            float zi = z_s[bb][jh], zf = z_s[bb][HH + jh], zg = z_s[bb][2 * HH + jh], zo = z_s[bb][3 * HH + jh];
            c1 = sigm(zf) * c1 + sigm(zi) * tanhf_(zg);
            h_s[1][bb][jh] = sigm(zo) * tanhf_(c1);
        }
        __syncthreads();
        // ----- layer 2 -----
        {
            float a[4] = { bs2, bs2, bs2, bs2 };
            const float4* wri = reinterpret_cast<const float4*>(w2i + (size_t)j * HH);
            const float4* wrh = reinterpret_cast<const float4*>(w2h + (size_t)j * HH);
#pragma unroll
            for (int k4 = 0; k4 < HH / 4; k4++) {
                float4 wiv = wri[k4];
                float4 whv = wrh[k4];
#pragma unroll
                for (int b = 0; b < 4; b++) {
                    float4 xv = reinterpret_cast<const float4*>(h_s[1][b])[k4];
                    float4 hv = reinterpret_cast<const float4*>(h_s[2][b])[k4];
                    a[b] += wiv.x * xv.x + wiv.y * xv.y + wiv.z * xv.z + wiv.w * xv.w
                          + whv.x * hv.x + whv.y * hv.y + whv.z * hv.z + whv.w * hv.w;
                }
            }
#pragma unroll
            for (int b = 0; b < 4; b++) z_s[b][j] = a[b];
        }
        __syncthreads();
        {
            float zi = z_s[bb][jh], zf = z_s[bb][HH + jh], zg = z_s[bb][2 * HH + jh], zo = z_s[bb][3 * HH + jh];
            c2 = sigm(zf) * c2 + sigm(zi) * tanhf_(zg);
            h_s[2][bb][jh] = sigm(zo) * tanhf_(c2);
        }
        __syncthreads();
        // ----- fc + feedback -----
        if (tid < 256) {
            const int w = tid >> 6, lane = tid & 63;
            float p = h_s[2][w][lane] * fcw_s[lane] + h_s[2][w][lane + 64] * fcw_s[lane + 64];
#pragma unroll
            for (int off = 32; off > 0; off >>= 1) p += __shfl_down(p, off);
            if (lane == 0) {
                float pr = p + fcbv;
                out[(size_t)(b0 + w) * NPRED + s] = pr;
                in0_s[w][0] = pr;
            }
        } else if (tid < 272) {
            int q = tid - 256;            // 0..15
            int b = q >> 2, k = q & 3;
            if (k > 0) in0_s[b][k] = 0.f; // zeros_feat
        }
        __syncthreads();
    }
}

extern "C" void kernel_launch(void* const* d_in, const int* in_sizes, int n_in,
                              void* d_out, int out_size, void* d_ws, size_t ws_size,
                              hipStream_t stream)
{
    const float* x = (const float*)d_in[0];
    const float* e0_wih = (const float*)d_in[1];
    const float* e0_whh = (const float*)d_in[2];
    const float* e0_bih = (const float*)d_in[3];
    const float* e0_bhh = (const float*)d_in[4];
    const float* e1_wih = (const float*)d_in[5];
    const float* e1_whh = (const float*)d_in[6];
    const float* e1_bih = (const float*)d_in[7];
    const float* e1_bhh = (const float*)d_in[8];
    const float* e2_wih = (const float*)d_in[9];
    const float* e2_whh = (const float*)d_in[10];
    const float* e2_bih = (const float*)d_in[11];
    const float* e2_bhh = (const float*)d_in[12];
    const float* fc_w = (const float*)d_in[25];
    const float* fc_b = (const float*)d_in[26];

    u16* ys = (u16*)d_ws;                                   // B*T*H bf16 = 33.5 MB
    size_t ys_bytes = (size_t)BB * TT * HH * sizeof(u16);
    float* hst = (float*)((char*)d_ws + ys_bytes);          // 3*B*H f32
    float* cst = hst + (size_t)3 * BB * HH;                 // 3*B*H f32
    const size_t BH = (size_t)BB * HH;

    k_scan0<<<dim3(256), dim3(512), 0, stream>>>(x, e0_wih, e0_whh, e0_bih, e0_bhh,
                                                 ys, hst, cst);
    k_scanL<<<dim3(256), dim3(512), 0, stream>>>(e1_wih, e1_whh, e1_bih, e1_bhh,
                                                 ys, 1, hst + BH, cst + BH);
    k_scanL<<<dim3(256), dim3(512), 0, stream>>>(e2_wih, e2_whh, e2_bih, e2_bhh,
                                                 ys, 0, hst + 2 * BH, cst + 2 * BH);
    k_decode<<<dim3(128), dim3(512), 0, stream>>>(
        x,
        (const float*)d_in[13], (const float*)d_in[14], (const float*)d_in[15], (const float*)d_in[16],
        (const float*)d_in[17], (const float*)d_in[18], (const float*)d_in[19], (const float*)d_in[20],
        (const float*)d_in[21], (const float*)d_in[22], (const float*)d_in[23], (const float*)d_in[24],
        fc_w, fc_b, hst, cst, (float*)d_out);
}

// Round 6
// 3750.230 us; speedup vs baseline: 4.3157x; 1.6505x over previous
//
#include <hip/hip_runtime.h>
#include <hip/hip_bf16.h>

#define HH 128     // hidden
#define G4 512     // 4*H
#define TT 256     // encoder timesteps
#define BB 512     // batch
#define NPRED 50   // decoder steps

typedef unsigned short u16;
typedef unsigned int u32;
typedef _Float16 h2_t __attribute__((ext_vector_type(2)));

__device__ __forceinline__ float sigm(float x) { return 1.0f / (1.0f + __expf(-x)); }
__device__ __forceinline__ float tanhf_(float x) { return 1.0f - 2.0f / (__expf(2.0f * x) + 1.0f); }
__device__ __forceinline__ float bf2f(u16 u) { return __uint_as_float(((u32)u) << 16); }
__device__ __forceinline__ u16 f2bf(float f) {
    u32 x = __float_as_uint(f);
    u32 r = (x + 0x7fffu + ((x >> 16) & 1u)) >> 16;   // RTNE
    return (u16)r;
}
__device__ __forceinline__ u32 pkh2(float a, float b) {
    u16 lo = __builtin_bit_cast(u16, (_Float16)a);
    u16 hi = __builtin_bit_cast(u16, (_Float16)b);
    return (u32)lo | ((u32)hi << 16);
}
__device__ __forceinline__ h2_t u2h(u32 u) { return __builtin_bit_cast(h2_t, u); }
__device__ __forceinline__ u16 f2h(float f) { return __builtin_bit_cast(u16, (_Float16)f); }

#if defined(__has_builtin)
#if __has_builtin(__builtin_amdgcn_fdot2)
#define HAVE_FDOT2 1
#endif
#endif
#ifdef HAVE_FDOT2
#define FDOT2(w, v, acc) __builtin_amdgcn_fdot2((w), (v), (acc), false)
#else
__device__ __forceinline__ float FDOT2(h2_t a, h2_t b, float c) {
    return c + (float)a.x * (float)b.x + (float)a.y * (float)b.y;
}
#endif

// ---------------------------------------------------------------------------
// Encoder layer 0. 1024 thr, 2 batch el/block, grid 256. Thread pair
// (row=tid>>1, half=tid&1) holds whh[row][half*64..+64) = 64 f32 VGPRs
// (~75 total, safely under the 128-VGPR cap at 4 waves/SIMD — no AGPR
// shuffling, unlike the 128-reg/thread round-3 version). Partner tid^1 in
// the same wave: combine with shfl_xor(.,1) (DPP, cheap).
// ---------------------------------------------------------------------------
__global__ void __launch_bounds__(1024) k_scan0(
    const float* __restrict__ x, const float* __restrict__ wih,
    const float* __restrict__ whh, const float* __restrict__ bih,
    const float* __restrict__ bhh, u16* __restrict__ ys,
    float* __restrict__ hst, float* __restrict__ cst)
{
    const int tid = threadIdx.x;
    const int row = tid >> 1, half = tid & 1, base = half * 64;
    const int b0 = blockIdx.x * 2;
    __shared__ __align__(16) float h_s[2][HH];
    __shared__ __align__(16) float z_s[2][G4];
    __shared__ float x_s[2][4];

    float wr[64];
    {
        const float4* wrow = reinterpret_cast<const float4*>(whh + (size_t)row * HH + base);
#pragma unroll
        for (int k4 = 0; k4 < 16; k4++) {
            float4 v = wrow[k4];
            wr[4 * k4] = v.x; wr[4 * k4 + 1] = v.y; wr[4 * k4 + 2] = v.z; wr[4 * k4 + 3] = v.w;
        }
    }
    float wi0 = 0.f, wi1 = 0.f, wi2 = 0.f, wi3 = 0.f, bias = 0.f;
    if (half == 0) {
        wi0 = wih[row * 4]; wi1 = wih[row * 4 + 1]; wi2 = wih[row * 4 + 2]; wi3 = wih[row * 4 + 3];
        bias = bih[row] + bhh[row];
    }
    const int bb = tid >> 7, jh = tid & 127;   // eltwise roles (tid < 256)
    float creg = 0.f;

    if (tid < 256) h_s[bb][jh] = 0.f;
    if (tid < 8) x_s[tid >> 2][tid & 3] = x[(size_t)(b0 + (tid >> 2)) * TT * 4 + (tid & 3)];
    __syncthreads();

    for (int t = 0; t < TT; t++) {
        float xnext = 0.f;
        if (tid < 8 && t + 1 < TT)
            xnext = x[(size_t)(b0 + (tid >> 2)) * TT * 4 + (size_t)(t + 1) * 4 + (tid & 3)];

        float a0 = 0.f, a1 = 0.f;
        if (half == 0) {
            a0 = bias + wi0 * x_s[0][0] + wi1 * x_s[0][1] + wi2 * x_s[0][2] + wi3 * x_s[0][3];
            a1 = bias + wi0 * x_s[1][0] + wi1 * x_s[1][1] + wi2 * x_s[1][2] + wi3 * x_s[1][3];
        }
#pragma unroll
        for (int k4 = 0; k4 < 16; k4++) {
            float4 h0 = reinterpret_cast<const float4*>(h_s[0] + base)[k4];
            a0 += wr[4 * k4] * h0.x + wr[4 * k4 + 1] * h0.y + wr[4 * k4 + 2] * h0.z + wr[4 * k4 + 3] * h0.w;
            float4 h1 = reinterpret_cast<const float4*>(h_s[1] + base)[k4];
            a1 += wr[4 * k4] * h1.x + wr[4 * k4 + 1] * h1.y + wr[4 * k4 + 2] * h1.z + wr[4 * k4 + 3] * h1.w;
        }
        a0 += __shfl_xor(a0, 1);
        a1 += __shfl_xor(a1, 1);
        if (half == 0) { z_s[0][row] = a0; z_s[1][row] = a1; }
        __syncthreads();

        if (tid < 256) {
            float zi = z_s[bb][jh], zf = z_s[bb][HH + jh], zg = z_s[bb][2 * HH + jh], zo = z_s[bb][3 * HH + jh];
            float c = sigm(zf) * creg + sigm(zi) * tanhf_(zg);
            float h = sigm(zo) * tanhf_(c);
            creg = c;
            h_s[bb][jh] = h;
            ys[((size_t)(b0 + bb) * TT + t) * HH + jh] = f2bf(h);
        }
        if (tid < 8 && t + 1 < TT) x_s[tid >> 2][tid & 3] = xnext;
        __syncthreads();
    }
    if (tid < 256) {
        hst[(size_t)(b0 + bb) * HH + jh] = h_s[bb][jh];
        cst[(size_t)(b0 + bb) * HH + jh] = creg;
    }
}

// ---------------------------------------------------------------------------
// Encoder layers 1,2. 1024 thr, 2 batch, grid 256. whh half-row in f32 regs
// (64), wih half-row as packed f16 in LDS (128 KiB — precedent: verified
// 128 KiB static-LDS 8-phase GEMM template on gfx950; [q][tid] chunk order so
// every ds_read_b128 is lane-dense) consumed by v_dot2_f32_f16. Input y as
// f16 in LDS. ~95 VGPRs — no spill, no AGPR round-trips.
// ---------------------------------------------------------------------------
__global__ void __launch_bounds__(1024) k_scanL(
    const float* __restrict__ wih, const float* __restrict__ whh,
    const float* __restrict__ bih, const float* __restrict__ bhh,
    u16* __restrict__ ys, int write_ys,
    float* __restrict__ hst, float* __restrict__ cst)
{
    const int tid = threadIdx.x;
    const int row = tid >> 1, half = tid & 1, base = half * 64;
    const int b0 = blockIdx.x * 2;
    __shared__ __align__(16) uint4 wih_lds[8][1024];     // 128 KiB packed f16
    __shared__ __align__(16) float h_s[2][HH];
    __shared__ __align__(16) u16  y_h[2][HH];            // f16 inputs
    __shared__ __align__(16) float z_s[2][G4];

    float wr[64];
    {
        const float4* wrow = reinterpret_cast<const float4*>(whh + (size_t)row * HH + base);
#pragma unroll
        for (int k4 = 0; k4 < 16; k4++) {
            float4 v = wrow[k4];
            wr[4 * k4] = v.x; wr[4 * k4 + 1] = v.y; wr[4 * k4 + 2] = v.z; wr[4 * k4 + 3] = v.w;
        }
    }
    // pack this thread's wih half-row (64 f32 -> 8 chunks of 8 f16) into LDS
#pragma unroll
    for (int q = 0; q < 8; q++) {
        const float4* src = reinterpret_cast<const float4*>(wih + (size_t)row * HH + base + q * 8);
        float4 v0 = src[0], v1 = src[1];
        uint4 pk;
        pk.x = pkh2(v0.x, v0.y); pk.y = pkh2(v0.z, v0.w);
        pk.z = pkh2(v1.x, v1.y); pk.w = pkh2(v1.z, v1.w);
        wih_lds[q][tid] = pk;
    }
    const float bias = bih[row] + bhh[row];   // used by half==0 at write
    const int bb = tid >> 7, jh = tid & 127;
    float creg = 0.f;

    if (tid < 256) {
        h_s[bb][jh] = 0.f;
        y_h[bb][jh] = f2h(bf2f(ys[((size_t)(b0 + bb) * TT) * HH + jh]));
    }
    __syncthreads();

    for (int t = 0; t < TT; t++) {
        u16 ynext = 0;
        if (tid < 256 && t + 1 < TT)
            ynext = ys[((size_t)(b0 + bb) * TT + (t + 1)) * HH + jh];

        float a0 = 0.f, a1 = 0.f;
        // wih * y  (f16 dot2, packed)
#pragma unroll
        for (int q = 0; q < 8; q++) {
            uint4 wq = wih_lds[q][tid];
            uint4 yq0 = *reinterpret_cast<const uint4*>(
                reinterpret_cast<const char*>(y_h[0]) + base * 2 + q * 16);
            uint4 yq1 = *reinterpret_cast<const uint4*>(
                reinterpret_cast<const char*>(y_h[1]) + base * 2 + q * 16);
            a0 = FDOT2(u2h(wq.x), u2h(yq0.x), a0);
            a0 = FDOT2(u2h(wq.y), u2h(yq0.y), a0);
            a0 = FDOT2(u2h(wq.z), u2h(yq0.z), a0);
            a0 = FDOT2(u2h(wq.w), u2h(yq0.w), a0);
            a1 = FDOT2(u2h(wq.x), u2h(yq1.x), a1);
            a1 = FDOT2(u2h(wq.y), u2h(yq1.y), a1);
            a1 = FDOT2(u2h(wq.z), u2h(yq1.z), a1);
            a1 = FDOT2(u2h(wq.w), u2h(yq1.w), a1);
        }
        // whh * h  (f32 regs)
#pragma unroll
        for (int k4 = 0; k4 < 16; k4++) {
            float4 h0 = reinterpret_cast<const float4*>(h_s[0] + base)[k4];
            a0 += wr[4 * k4] * h0.x + wr[4 * k4 + 1] * h0.y + wr[4 * k4 + 2] * h0.z + wr[4 * k4 + 3] * h0.w;
            float4 h1 = reinterpret_cast<const float4*>(h_s[1] + base)[k4];
            a1 += wr[4 * k4] * h1.x + wr[4 * k4 + 1] * h1.y + wr[4 * k4 + 2] * h1.z + wr[4 * k4 + 3] * h1.w;
        }
        a0 += __shfl_xor(a0, 1);
        a1 += __shfl_xor(a1, 1);
        if (half == 0) { z_s[0][row] = a0 + bias; z_s[1][row] = a1 + bias; }
        __syncthreads();

        if (tid < 256) {
            float zi = z_s[bb][jh], zf = z_s[bb][HH + jh], zg = z_s[bb][2 * HH + jh], zo = z_s[bb][3 * HH + jh];
            float c = sigm(zf) * creg + sigm(zi) * tanhf_(zg);
            float h = sigm(zo) * tanhf_(c);
            creg = c;
            h_s[bb][jh] = h;
            if (write_ys) ys[((size_t)(b0 + bb) * TT + t) * HH + jh] = f2bf(h);
            if (t + 1 < TT) y_h[bb][jh] = f2h(bf2f(ynext));
        }
        __syncthreads();
    }
    if (tid < 256) {
        hst[(size_t)(b0 + bb) * HH + jh] = h_s[bb][jh];
        cst[(size_t)(b0 + bb) * HH + jh] = creg;
    }
}

// ---------------------------------------------------------------------------
// Pack the 5 decoder 512x128 matrices (w0h,w1i,w1h,w2i,w2h) to f16 pairs in
// the exact per-thread chunk order k_decode reads: u32 index
// o = ((m*4+p)*512 + t)*16 + u ; row = p*128 + (t>>2); col = (t&3)*32 + 2u.
// ---------------------------------------------------------------------------
__global__ void __launch_bounds__(256) k_pack(
    const float* __restrict__ w0h, const float* __restrict__ w1i,
    const float* __restrict__ w1h, const float* __restrict__ w2i,
    const float* __restrict__ w2h, u32* __restrict__ wpk)
{
    int o = blockIdx.x * 256 + threadIdx.x;      // 0 .. 163839
    int m = o >> 15;
    int rem = o & 32767;
    int p = rem >> 13;
    int rem2 = rem & 8191;
    int t = rem2 >> 4;
    int u = rem2 & 15;
    int row = p * 128 + (t >> 2);
    int col = (t & 3) * 32 + 2 * u;
    const float* src = (m == 0) ? w0h : (m == 1) ? w1i : (m == 2) ? w1h : (m == 3) ? w2i : w2h;
    float v0 = src[row * 128 + col], v1 = src[row * 128 + col + 1];
    wpk[o] = pkh2(v0, v1);
}

// ---------------------------------------------------------------------------
// Decoder: 50 steps x 3 layers. 512 thr, 4 batch, grid 128. Weights are the
// coalesced packed-f16 stream (wpk, L2-resident per XCD: 640 KB working set,
// 64B/lane dense chunks); h-vectors live in LDS as f16 and feed
// v_dot2_f32_f16. 4 lanes per output row; quad shfl_xor reduce (DPP).
// Round-3 version read f32 rows lane-strided (64 lines/instr) -> 2.8 GB HBM
// overfetch, 2.23 ms.
// ---------------------------------------------------------------------------
__global__ void __launch_bounds__(512) k_decode(
    const float* __restrict__ x,
    const float* __restrict__ w0i,
    const float* __restrict__ b0i, const float* __restrict__ b0h,
    const float* __restrict__ b1i, const float* __restrict__ b1h,
    const float* __restrict__ b2i, const float* __restrict__ b2h,
    const float* __restrict__ fcw, const float* __restrict__ fcb,
    const float* __restrict__ hst, const float* __restrict__ cst,
    const uint4* __restrict__ wpk,
    float* __restrict__ out)
{
    const int tid = threadIdx.x;
    const int b0 = blockIdx.x * 4;
    const int r = tid >> 2;        // output row within gate-block
    const int g = tid & 3;         // col-group (32 cols)
    __shared__ __align__(16) u16  h_h[3][4][HH];     // f16 hidden states
    __shared__ __align__(16) float h2f_s[4][HH];     // f32 copy of layer-2 h (fc)
    __shared__ __align__(16) float z_s[4][G4];
    __shared__ __align__(16) float in0_s[4][4];
    __shared__ __align__(16) float fcw_s[HH];

    const int bb = tid >> 7, jh = tid & 127;
    float c0 = cst[((size_t)0 * BB + b0 + bb) * HH + jh];
    float c1 = cst[((size_t)1 * BB + b0 + bb) * HH + jh];
    float c2 = cst[((size_t)2 * BB + b0 + bb) * HH + jh];
    h_h[0][bb][jh] = f2h(hst[((size_t)0 * BB + b0 + bb) * HH + jh]);
    h_h[1][bb][jh] = f2h(hst[((size_t)1 * BB + b0 + bb) * HH + jh]);
    h_h[2][bb][jh] = f2h(hst[((size_t)2 * BB + b0 + bb) * HH + jh]);
    if (tid < HH) fcw_s[tid] = fcw[tid];
    if (tid < 16) in0_s[tid >> 2][tid & 3] = x[(size_t)(b0 + (tid >> 2)) * TT * 4 + (size_t)(TT - 1) * 4 + (tid & 3)];

    float bs0[4], bs1[4], bs2[4], wi0r[4][4];
#pragma unroll
    for (int p = 0; p < 4; p++) {
        int rowp = p * 128 + r;
        bs0[p] = b0i[rowp] + b0h[rowp];
        bs1[p] = b1i[rowp] + b1h[rowp];
        bs2[p] = b2i[rowp] + b2h[rowp];
#pragma unroll
        for (int k = 0; k < 4; k++) wi0r[p][k] = w0i[rowp * 4 + k];
    }
    const float fcbv = fcb[0];
    __syncthreads();

#define VEC_CHUNK(l, b, q) (*reinterpret_cast<const uint4*>( \
        reinterpret_cast<const char*>(&h_h[l][b][0]) + g * 64 + (q) * 16))

    for (int s = 0; s < NPRED; s++) {
        // ================= layer 0: z = w0i*in0 + w0h*h0 =================
#pragma unroll
        for (int p = 0; p < 4; p++) {
            float a[4] = {0.f, 0.f, 0.f, 0.f};
            const uint4* wh_c = wpk + (((0 * 4 + p) * 512 + tid) << 2);
#pragma unroll
            for (int q = 0; q < 4; q++) {
                uint4 w4 = wh_c[q];
#pragma unroll
                for (int b = 0; b < 4; b++) {
                    uint4 v = VEC_CHUNK(0, b, q);
                    a[b] = FDOT2(u2h(w4.x), u2h(v.x), a[b]);
                    a[b] = FDOT2(u2h(w4.y), u2h(v.y), a[b]);
                    a[b] = FDOT2(u2h(w4.z), u2h(v.z), a[b]);
                    a[b] = FDOT2(u2h(w4.w), u2h(v.w), a[b]);
                }
            }
#pragma unroll
            for (int b = 0; b < 4; b++) {
                a[b] += __shfl_xor(a[b], 1);
                a[b] += __shfl_xor(a[b], 2);
            }
            if (g == 0) {
#pragma unroll
                for (int b = 0; b < 4; b++) {
                    float wi = wi0r[p][0] * in0_s[b][0] + wi0r[p][1] * in0_s[b][1]
                             + wi0r[p][2] * in0_s[b][2] + wi0r[p][3] * in0_s[b][3];
                    z_s[b][p * 128 + r] = a[b] + bs0[p] + wi;
                }
            }
        }
        __syncthreads();
        {
            float zi = z_s[bb][jh], zf = z_s[bb][HH + jh], zg = z_s[bb][2 * HH + jh], zo = z_s[bb][3 * HH + jh];
            c0 = sigm(zf) * c0 + sigm(zi) * tanhf_(zg);
            float h = sigm(zo) * tanhf_(c0);
            h_h[0][bb][jh] = f2h(h);
        }
        __syncthreads();
        // ================= layer 1: z = w1i*h0 + w1h*h1 =================
#pragma unroll
        for (int p = 0; p < 4; p++) {
            float a[4] = {0.f, 0.f, 0.f, 0.f};
            const uint4* wi_c = wpk + (((1 * 4 + p) * 512 + tid) << 2);
            const uint4* wh_c = wpk + (((2 * 4 + p) * 512 + tid) << 2);
#pragma unroll
            for (int q = 0; q < 4; q++) {
                uint4 wi4 = wi_c[q], wh4 = wh_c[q];
#pragma unroll
                for (int b = 0; b < 4; b++) {
                    uint4 vi = VEC_CHUNK(0, b, q);
                    uint4 vh = VEC_CHUNK(1, b, q);
                    a[b] = FDOT2(u2h(wi4.x), u2h(vi.x), a[b]);
                    a[b] = FDOT2(u2h(wi4.y), u2h(vi.y), a[b]);
                    a[b] = FDOT2(u2h(wi4.z), u2h(vi.z), a[b]);
                    a[b] = FDOT2(u2h(wi4.w), u2h(vi.w), a[b]);
                    a[b] = FDOT2(u2h(wh4.x), u2h(vh.x), a[b]);
                    a[b] = FDOT2(u2h(wh4.y), u2h(vh.y), a[b]);
                    a[b] = FDOT2(u2h(wh4.z), u2h(vh.z), a[b]);
                    a[b] = FDOT2(u2h(wh4.w), u2h(vh.w), a[b]);
                }
            }
#pragma unroll
            for (int b = 0; b < 4; b++) {
                a[b] += __shfl_xor(a[b], 1);
                a[b] += __shfl_xor(a[b], 2);
            }
            if (g == 0) {
#pragma unroll
                for (int b = 0; b < 4; b++) z_s[b][p * 128 + r] = a[b] + bs1[p];
            }
        }
        __syncthreads();
        {
            float zi = z_s[bb][jh], zf = z_s[bb][HH + jh], zg = z_s[bb][2 * HH + jh], zo = z_s[bb][3 * HH + jh];
            c1 = sigm(zf) * c1 + sigm(zi) * tanhf_(zg);
            float h = sigm(zo) * tanhf_(c1);
            h_h[1][bb][jh] = f2h(h);
        }
        __syncthreads();
        // ================= layer 2: z = w2i*h1 + w2h*h2 =================
#pragma unroll
        for (int p = 0; p < 4; p++) {
            float a[4] = {0.f, 0.f, 0.f, 0.f};
            const uint4* wi_c = wpk + (((3 * 4 + p) * 512 + tid) << 2);
            const uint4* wh_c = wpk + (((4 * 4 + p) * 512 + tid) << 2);
#pragma unroll
            for (int q = 0; q < 4; q++) {
                uint4 wi4 = wi_c[q], wh4 = wh_c[q];
#pragma unroll
                for (int b = 0; b < 4; b++) {
                    uint4 vi = VEC_CHUNK(1, b, q);
                    uint4 vh = VEC_CHUNK(2, b, q);
                    a[b] = FDOT2(u2h(wi4.x), u2h(vi.x), a[b]);
                    a[b] = FDOT2(u2h(wi4.y), u2h(vi.y), a[b]);
                    a[b] = FDOT2(u2h(wi4.z), u2h(vi.z), a[b]);
                    a[b] = FDOT2(u2h(wi4.w), u2h(vi.w), a[b]);
                    a[b] = FDOT2(u2h(wh4.x), u2h(vh.x), a[b]);
                    a[b] = FDOT2(u2h(wh4.y), u2h(vh.y), a[b]);
                    a[b] = FDOT2(u2h(wh4.z), u2h(vh.z), a[b]);
                    a[b] = FDOT2(u2h(wh4.w), u2h(vh.w), a[b]);
                }
            }
#pragma unroll
            for (int b = 0; b < 4; b++) {
                a[b] += __shfl_xor(a[b], 1);
                a[b] += __shfl_xor(a[b], 2);
            }
            if (g == 0) {
#pragma unroll
                for (int b = 0; b < 4; b++) z_s[b][p * 128 + r] = a[b] + bs2[p];
            }
        }
        __syncthreads();
        {
            float zi = z_s[bb][jh], zf = z_s[bb][HH + jh], zg = z_s[bb][2 * HH + jh], zo = z_s[bb][3 * HH + jh];
            c2 = sigm(zf) * c2 + sigm(zi) * tanhf_(zg);
            float h = sigm(zo) * tanhf_(c2);
            h_h[2][bb][jh] = f2h(h);
            h2f_s[bb][jh] = h;
        }
        __syncthreads();
        // ----- fc + feedback -----
        if (tid < 256) {
            const int w = tid >> 6, lane = tid & 63;
            float p = h2f_s[w][lane] * fcw_s[lane] + h2f_s[w][lane + 64] * fcw_s[lane + 64];
#pragma unroll
            for (int off = 32; off > 0; off >>= 1) p += __shfl_down(p, off);
            if (lane == 0) {
                float pr = p + fcbv;
                out[(size_t)(b0 + w) * NPRED + s] = pr;
                in0_s[w][0] = pr;
            }
        } else if (tid < 272) {
            int q = tid - 256;            // 0..15
            int b = q >> 2, k = q & 3;
            if (k > 0) in0_s[b][k] = 0.f; // zeros_feat
        }
        __syncthreads();
    }
#undef VEC_CHUNK
}

extern "C" void kernel_launch(void* const* d_in, const int* in_sizes, int n_in,
                              void* d_out, int out_size, void* d_ws, size_t ws_size,
                              hipStream_t stream)
{
    const float* x = (const float*)d_in[0];
    const float* e0_wih = (const float*)d_in[1];
    const float* e0_whh = (const float*)d_in[2];
    const float* e0_bih = (const float*)d_in[3];
    const float* e0_bhh = (const float*)d_in[4];
    const float* e1_wih = (const float*)d_in[5];
    const float* e1_whh = (const float*)d_in[6];
    const float* e1_bih = (const float*)d_in[7];
    const float* e1_bhh = (const float*)d_in[8];
    const float* e2_wih = (const float*)d_in[9];
    const float* e2_whh = (const float*)d_in[10];
    const float* e2_bih = (const float*)d_in[11];
    const float* e2_bhh = (const float*)d_in[12];
    const float* d0_wih = (const float*)d_in[13];
    const float* d0_whh = (const float*)d_in[14];
    const float* d0_bih = (const float*)d_in[15];
    const float* d0_bhh = (const float*)d_in[16];
    const float* d1_wih = (const float*)d_in[17];
    const float* d1_whh = (const float*)d_in[18];
    const float* d1_bih = (const float*)d_in[19];
    const float* d1_bhh = (const float*)d_in[20];
    const float* d2_wih = (const float*)d_in[21];
    const float* d2_whh = (const float*)d_in[22];
    const float* d2_bih = (const float*)d_in[23];
    const float* d2_bhh = (const float*)d_in[24];
    const float* fc_w = (const float*)d_in[25];
    const float* fc_b = (const float*)d_in[26];

    // workspace layout
    u16* ys = (u16*)d_ws;                                   // B*T*H bf16 = 33.5 MB
    size_t ys_bytes = (size_t)BB * TT * HH * sizeof(u16);
    float* hst = (float*)((char*)d_ws + ys_bytes);          // 3*B*H f32
    float* cst = hst + (size_t)3 * BB * HH;                 // 3*B*H f32
    u32* wpk = (u32*)(cst + (size_t)3 * BB * HH);           // 163840 u32 = 640 KB
    const size_t BH = (size_t)BB * HH;

    k_pack<<<dim3(640), dim3(256), 0, stream>>>(d0_whh, d1_wih, d1_whh, d2_wih, d2_whh, wpk);
    k_scan0<<<dim3(256), dim3(1024), 0, stream>>>(x, e0_wih, e0_whh, e0_bih, e0_bhh,
                                                  ys, hst, cst);
    k_scanL<<<dim3(256), dim3(1024), 0, stream>>>(e1_wih, e1_whh, e1_bih, e1_bhh,
                                                  ys, 1, hst + BH, cst + BH);
    k_scanL<<<dim3(256), dim3(1024), 0, stream>>>(e2_wih, e2_whh, e2_bih, e2_bhh,
                                                  ys, 0, hst + 2 * BH, cst + 2 * BH);
    k_decode<<<dim3(128), dim3(512), 0, stream>>>(
        x, d0_wih, d0_bih, d0_bhh, d1_bih, d1_bhh, d2_bih, d2_bhh,
        fc_w, fc_b, hst, cst, (const uint4*)wpk, (float*)d_out);
}

// Round 9
// 2800.634 us; speedup vs baseline: 5.7790x; 1.3391x over previous
//
#include <hip/hip_runtime.h>
#include <hip/hip_bf16.h>

#define HH 128     // hidden
#define G4 512     // 4*H
#define TT 256     // encoder timesteps
#define BB 512     // batch
#define NPRED 50   // decoder steps

typedef unsigned short u16;
typedef unsigned int u32;
typedef _Float16 h2_t __attribute__((ext_vector_type(2)));

__device__ __forceinline__ float sigm(float x) { return 1.0f / (1.0f + __expf(-x)); }
__device__ __forceinline__ float tanhf_(float x) { return 1.0f - 2.0f / (__expf(2.0f * x) + 1.0f); }
__device__ __forceinline__ float bf2f(u16 u) { return __uint_as_float(((u32)u) << 16); }
__device__ __forceinline__ u16 f2bf(float f) {
    u32 x = __float_as_uint(f);
    u32 r = (x + 0x7fffu + ((x >> 16) & 1u)) >> 16;   // RTNE
    return (u16)r;
}
__device__ __forceinline__ u32 pkh2(float a, float b) {
    u16 lo = __builtin_bit_cast(u16, (_Float16)a);
    u16 hi = __builtin_bit_cast(u16, (_Float16)b);
    return (u32)lo | ((u32)hi << 16);
}
__device__ __forceinline__ h2_t u2h(u32 u) { return __builtin_bit_cast(h2_t, u); }
__device__ __forceinline__ u16 f2h(float f) { return __builtin_bit_cast(u16, (_Float16)f); }

#if defined(__has_builtin)
#if __has_builtin(__builtin_amdgcn_fdot2)
#define HAVE_FDOT2 1
#endif
#endif
#ifdef HAVE_FDOT2
#define FDOT2(w, v, acc) __builtin_amdgcn_fdot2((w), (v), (acc), false)
#else
__device__ __forceinline__ float FDOT2(h2_t a, h2_t b, float c) {
    return c + (float)a.x * (float)b.x + (float)a.y * (float)b.y;
}
#endif

// ---------------------------------------------------------------------------
// Encoder layer 0. 1024 thr, 2 batch el/block, grid 256.
// Thread pair (row=tid>>1, half=tid&1): whh half-row packed f16 in 32 u32
// VGPRs (round-6 f32 version read h as f32 from LDS: 32 b128/thread/step and
// 1.3e8 bank-conflict cycles — scans are LDS-throughput-bound). h stored f16
// in LDS: 16 b128/thread/step. ~60 VGPRs.
// ---------------------------------------------------------------------------
__global__ void __launch_bounds__(1024) k_scan0(
    const float* __restrict__ x, const float* __restrict__ wih,
    const float* __restrict__ whh, const float* __restrict__ bih,
    const float* __restrict__ bhh, u16* __restrict__ ys,
    float* __restrict__ hst, float* __restrict__ cst)
{
    const int tid = threadIdx.x;
    const int row = tid >> 1, half = tid & 1, base = half * 64;
    const int b0 = blockIdx.x * 2;
    __shared__ __align__(16) u16  h_h[2][HH];    // f16 hidden state
    __shared__ __align__(16) float z_s[2][G4];
    __shared__ float x_s[2][4];

    u32 wph[32];   // whh[row][base..base+64) as 32 f16-pairs
    {
        const float2* wrow = reinterpret_cast<const float2*>(whh + (size_t)row * HH + base);
#pragma unroll
        for (int k2 = 0; k2 < 32; k2++) {
            float2 v = wrow[k2];
            wph[k2] = pkh2(v.x, v.y);
        }
    }
    float wi0 = 0.f, wi1 = 0.f, wi2 = 0.f, wi3 = 0.f, bias = 0.f;
    if (half == 0) {
        wi0 = wih[row * 4]; wi1 = wih[row * 4 + 1]; wi2 = wih[row * 4 + 2]; wi3 = wih[row * 4 + 3];
        bias = bih[row] + bhh[row];
    }
    const int bb = tid >> 7, jh = tid & 127;   // eltwise roles (tid < 256)
    float creg = 0.f, hreg = 0.f;

    if (tid < 256) h_h[bb][jh] = 0;
    if (tid < 8) x_s[tid >> 2][tid & 3] = x[(size_t)(b0 + (tid >> 2)) * TT * 4 + (tid & 3)];
    __syncthreads();

    for (int t = 0; t < TT; t++) {
        float xnext = 0.f;
        if (tid < 8 && t + 1 < TT)
            xnext = x[(size_t)(b0 + (tid >> 2)) * TT * 4 + (size_t)(t + 1) * 4 + (tid & 3)];

        float a0 = 0.f, a1 = 0.f;
        if (half == 0) {
            a0 = bias + wi0 * x_s[0][0] + wi1 * x_s[0][1] + wi2 * x_s[0][2] + wi3 * x_s[0][3];
            a1 = bias + wi0 * x_s[1][0] + wi1 * x_s[1][1] + wi2 * x_s[1][2] + wi3 * x_s[1][3];
        }
#pragma unroll
        for (int q = 0; q < 8; q++) {
            uint4 hq0 = *reinterpret_cast<const uint4*>(
                reinterpret_cast<const char*>(h_h[0]) + base * 2 + q * 16);
            uint4 hq1 = *reinterpret_cast<const uint4*>(
                reinterpret_cast<const char*>(h_h[1]) + base * 2 + q * 16);
            u32 w0 = wph[4 * q], w1 = wph[4 * q + 1], w2 = wph[4 * q + 2], w3 = wph[4 * q + 3];
            a0 = FDOT2(u2h(w0), u2h(hq0.x), a0);
            a0 = FDOT2(u2h(w1), u2h(hq0.y), a0);
            a0 = FDOT2(u2h(w2), u2h(hq0.z), a0);
            a0 = FDOT2(u2h(w3), u2h(hq0.w), a0);
            a1 = FDOT2(u2h(w0), u2h(hq1.x), a1);
            a1 = FDOT2(u2h(w1), u2h(hq1.y), a1);
            a1 = FDOT2(u2h(w2), u2h(hq1.z), a1);
            a1 = FDOT2(u2h(w3), u2h(hq1.w), a1);
        }
        a0 += __shfl_xor(a0, 1);
        a1 += __shfl_xor(a1, 1);
        if (half == 0) { z_s[0][row] = a0; z_s[1][row] = a1; }
        __syncthreads();

        if (tid < 256) {
            float zi = z_s[bb][jh], zf = z_s[bb][HH + jh], zg = z_s[bb][2 * HH + jh], zo = z_s[bb][3 * HH + jh];
            float c = sigm(zf) * creg + sigm(zi) * tanhf_(zg);
            float h = sigm(zo) * tanhf_(c);
            creg = c; hreg = h;
            h_h[bb][jh] = f2h(h);
            ys[((size_t)(b0 + bb) * TT + t) * HH + jh] = f2bf(h);
        }
        if (tid < 8 && t + 1 < TT) x_s[tid >> 2][tid & 3] = xnext;
        __syncthreads();
    }
    if (tid < 256) {
        hst[(size_t)(b0 + bb) * HH + jh] = hreg;
        cst[(size_t)(b0 + bb) * HH + jh] = creg;
    }
}

// ---------------------------------------------------------------------------
// Encoder layers 1,2. 1024 thr, 2 batch, grid 256. BOTH whh and wih half-rows
// packed f16 in registers (64 u32 persistent, ~110 VGPRs < 128 cap); h and y
// stored f16 in LDS. Per-thread LDS reads/step: 32 b128 (was 56 with f32-h +
// LDS wih + 128 KiB wih array). Removes the round-6 LDS-BW bottleneck.
// ---------------------------------------------------------------------------
__global__ void __launch_bounds__(1024) k_scanL(
    const float* __restrict__ wih, const float* __restrict__ whh,
    const float* __restrict__ bih, const float* __restrict__ bhh,
    u16* __restrict__ ys, int write_ys,
    float* __restrict__ hst, float* __restrict__ cst)
{
    const int tid = threadIdx.x;
    const int row = tid >> 1, half = tid & 1, base = half * 64;
    const int b0 = blockIdx.x * 2;
    __shared__ __align__(16) u16  h_h[2][HH];    // f16 hidden
    __shared__ __align__(16) u16  y_h[2][HH];    // f16 layer input
    __shared__ __align__(16) float z_s[2][G4];

    u32 wph[32], wpi[32];
    {
        const float2* wrow = reinterpret_cast<const float2*>(whh + (size_t)row * HH + base);
        const float2* irow = reinterpret_cast<const float2*>(wih + (size_t)row * HH + base);
#pragma unroll
        for (int k2 = 0; k2 < 32; k2++) {
            float2 v = wrow[k2]; wph[k2] = pkh2(v.x, v.y);
            float2 w = irow[k2]; wpi[k2] = pkh2(w.x, w.y);
        }
    }
    const float bias = bih[row] + bhh[row];   // used by half==0 at write
    const int bb = tid >> 7, jh = tid & 127;
    float creg = 0.f, hreg = 0.f;

    if (tid < 256) {
        h_h[bb][jh] = 0;
        y_h[bb][jh] = f2h(bf2f(ys[((size_t)(b0 + bb) * TT) * HH + jh]));
    }
    __syncthreads();

    for (int t = 0; t < TT; t++) {
        u16 ynext = 0;
        if (tid < 256 && t + 1 < TT)
            ynext = ys[((size_t)(b0 + bb) * TT + (t + 1)) * HH + jh];

        float a0 = 0.f, a1 = 0.f;
#pragma unroll
        for (int q = 0; q < 8; q++) {
            uint4 hq0 = *reinterpret_cast<const uint4*>(
                reinterpret_cast<const char*>(h_h[0]) + base * 2 + q * 16);
            uint4 hq1 = *reinterpret_cast<const uint4*>(
                reinterpret_cast<const char*>(h_h[1]) + base * 2 + q * 16);
            uint4 yq0 = *reinterpret_cast<const uint4*>(
                reinterpret_cast<const char*>(y_h[0]) + base * 2 + q * 16);
            uint4 yq1 = *reinterpret_cast<const uint4*>(
                reinterpret_cast<const char*>(y_h[1]) + base * 2 + q * 16);
            u32 h0 = wph[4 * q], h1 = wph[4 * q + 1], h2 = wph[4 * q + 2], h3 = wph[4 * q + 3];
            u32 i0 = wpi[4 * q], i1 = wpi[4 * q + 1], i2 = wpi[4 * q + 2], i3 = wpi[4 * q + 3];
            a0 = FDOT2(u2h(h0), u2h(hq0.x), a0);
            a0 = FDOT2(u2h(h1), u2h(hq0.y), a0);
            a0 = FDOT2(u2h(h2), u2h(hq0.z), a0);
            a0 = FDOT2(u2h(h3), u2h(hq0.w), a0);
            a0 = FDOT2(u2h(i0), u2h(yq0.x), a0);
            a0 = FDOT2(u2h(i1), u2h(yq0.y), a0);
            a0 = FDOT2(u2h(i2), u2h(yq0.z), a0);
            a0 = FDOT2(u2h(i3), u2h(yq0.w), a0);
            a1 = FDOT2(u2h(h0), u2h(hq1.x), a1);
            a1 = FDOT2(u2h(h1), u2h(hq1.y), a1);
            a1 = FDOT2(u2h(h2), u2h(hq1.z), a1);
            a1 = FDOT2(u2h(h3), u2h(hq1.w), a1);
            a1 = FDOT2(u2h(i0), u2h(yq1.x), a1);
            a1 = FDOT2(u2h(i1), u2h(yq1.y), a1);
            a1 = FDOT2(u2h(i2), u2h(yq1.z), a1);
            a1 = FDOT2(u2h(i3), u2h(yq1.w), a1);
        }
        a0 += __shfl_xor(a0, 1);
        a1 += __shfl_xor(a1, 1);
        if (half == 0) { z_s[0][row] = a0 + bias; z_s[1][row] = a1 + bias; }
        __syncthreads();

        if (tid < 256) {
            float zi = z_s[bb][jh], zf = z_s[bb][HH + jh], zg = z_s[bb][2 * HH + jh], zo = z_s[bb][3 * HH + jh];
            float c = sigm(zf) * creg + sigm(zi) * tanhf_(zg);
            float h = sigm(zo) * tanhf_(c);
            creg = c; hreg = h;
            h_h[bb][jh] = f2h(h);
            if (write_ys) ys[((size_t)(b0 + bb) * TT + t) * HH + jh] = f2bf(h);
            if (t + 1 < TT) y_h[bb][jh] = f2h(bf2f(ynext));
        }
        __syncthreads();
    }
    if (tid < 256) {
        hst[(size_t)(b0 + bb) * HH + jh] = hreg;
        cst[(size_t)(b0 + bb) * HH + jh] = creg;
    }
}

// ---------------------------------------------------------------------------
// Pack the 5 decoder 512x128 matrices (w0h,w1i,w1h,w2i,w2h) to f16 pairs in
// the exact per-thread chunk order k_decode reads: u32 index
// o = ((m*4+p)*512 + t)*16 + u ; row = p*128 + (t>>2); col = (t&3)*32 + 2u.
// ---------------------------------------------------------------------------
__global__ void __launch_bounds__(256) k_pack(
    const float* __restrict__ w0h, const float* __restrict__ w1i,
    const float* __restrict__ w1h, const float* __restrict__ w2i,
    const float* __restrict__ w2h, u32* __restrict__ wpk)
{
    int o = blockIdx.x * 256 + threadIdx.x;      // 0 .. 163839
    int m = o >> 15;
    int rem = o & 32767;
    int p = rem >> 13;
    int rem2 = rem & 8191;
    int t = rem2 >> 4;
    int u = rem2 & 15;
    int row = p * 128 + (t >> 2);
    int col = (t & 3) * 32 + 2 * u;
    const float* src = (m == 0) ? w0h : (m == 1) ? w1i : (m == 2) ? w1h : (m == 3) ? w2i : w2h;
    float v0 = src[row * 128 + col], v1 = src[row * 128 + col + 1];
    wpk[o] = pkh2(v0, v1);
}

// ---------------------------------------------------------------------------
// Decoder: 50 steps x 3 layers. 512 thr, 4 batch, grid 128. Weights are the
// coalesced packed-f16 stream (wpk, 640 KB, L2-resident). Round-6 ran with
// default launch bounds -> VGPR capped at 128 -> scratch spill (FETCH 1.08 GB,
// WRITE 123 MB per dispatch). __launch_bounds__(512,1) lifts the budget to
// 256 regs (1 block/CU is free: grid 128 < 256 CUs).
// ---------------------------------------------------------------------------
__global__ void __launch_bounds__(512, 1) k_decode(
    const float* __restrict__ x,
    const float* __restrict__ w0i,
    const float* __restrict__ b0i, const float* __restrict__ b0h,
    const float* __restrict__ b1i, const float* __restrict__ b1h,
    const float* __restrict__ b2i, const float* __restrict__ b2h,
    const float* __restrict__ fcw, const float* __restrict__ fcb,
    const float* __restrict__ hst, const float* __restrict__ cst,
    const uint4* __restrict__ wpk,
    float* __restrict__ out)
{
    const int tid = threadIdx.x;
    const int b0 = blockIdx.x * 4;
    const int r = tid >> 2;        // output row within gate-block
    const int g = tid & 3;         // col-group (32 cols)
    __shared__ __align__(16) u16  h_h[3][4][HH];     // f16 hidden states
    __shared__ __align__(16) float h2f_s[4][HH];     // f32 copy of layer-2 h (fc)
    __shared__ __align__(16) float z_s[4][G4];
    __shared__ __align__(16) float in0_s[4][4];
    __shared__ __align__(16) float fcw_s[HH];

    const int bb = tid >> 7, jh = tid & 127;
    float c0 = cst[((size_t)0 * BB + b0 + bb) * HH + jh];
    float c1 = cst[((size_t)1 * BB + b0 + bb) * HH + jh];
    float c2 = cst[((size_t)2 * BB + b0 + bb) * HH + jh];
    h_h[0][bb][jh] = f2h(hst[((size_t)0 * BB + b0 + bb) * HH + jh]);
    h_h[1][bb][jh] = f2h(hst[((size_t)1 * BB + b0 + bb) * HH + jh]);
    h_h[2][bb][jh] = f2h(hst[((size_t)2 * BB + b0 + bb) * HH + jh]);
    if (tid < HH) fcw_s[tid] = fcw[tid];
    if (tid < 16) in0_s[tid >> 2][tid & 3] = x[(size_t)(b0 + (tid >> 2)) * TT * 4 + (size_t)(TT - 1) * 4 + (tid & 3)];

    float bs0[4], bs1[4], bs2[4], wi0r[4][4];
#pragma unroll
    for (int p = 0; p < 4; p++) {
        int rowp = p * 128 + r;
        bs0[p] = b0i[rowp] + b0h[rowp];
        bs1[p] = b1i[rowp] + b1h[rowp];
        bs2[p] = b2i[rowp] + b2h[rowp];
#pragma unroll
        for (int k = 0; k < 4; k++) wi0r[p][k] = w0i[rowp * 4 + k];
    }
    const float fcbv = fcb[0];
    __syncthreads();

#define VEC_CHUNK(l, b, q) (*reinterpret_cast<const uint4*>( \
        reinterpret_cast<const char*>(&h_h[l][b][0]) + g * 64 + (q) * 16))

    for (int s = 0; s < NPRED; s++) {
        // ================= layer 0: z = w0i*in0 + w0h*h0 =================
#pragma unroll
        for (int p = 0; p < 4; p++) {
            float a[4] = {0.f, 0.f, 0.f, 0.f};
            const uint4* wh_c = wpk + (((0 * 4 + p) * 512 + tid) << 2);
#pragma unroll
            for (int q = 0; q < 4; q++) {
                uint4 w4 = wh_c[q];
#pragma unroll
                for (int b = 0; b < 4; b++) {
                    uint4 v = VEC_CHUNK(0, b, q);
                    a[b] = FDOT2(u2h(w4.x), u2h(v.x), a[b]);
                    a[b] = FDOT2(u2h(w4.y), u2h(v.y), a[b]);
                    a[b] = FDOT2(u2h(w4.z), u2h(v.z), a[b]);
                    a[b] = FDOT2(u2h(w4.w), u2h(v.w), a[b]);
                }
            }
#pragma unroll
            for (int b = 0; b < 4; b++) {
                a[b] += __shfl_xor(a[b], 1);
                a[b] += __shfl_xor(a[b], 2);
            }
            if (g == 0) {
#pragma unroll
                for (int b = 0; b < 4; b++) {
                    float wi = wi0r[p][0] * in0_s[b][0] + wi0r[p][1] * in0_s[b][1]
                             + wi0r[p][2] * in0_s[b][2] + wi0r[p][3] * in0_s[b][3];
                    z_s[b][p * 128 + r] = a[b] + bs0[p] + wi;
                }
            }
        }
        __syncthreads();
        {
            float zi = z_s[bb][jh], zf = z_s[bb][HH + jh], zg = z_s[bb][2 * HH + jh], zo = z_s[bb][3 * HH + jh];
            c0 = sigm(zf) * c0 + sigm(zi) * tanhf_(zg);
            float h = sigm(zo) * tanhf_(c0);
            h_h[0][bb][jh] = f2h(h);
        }
        __syncthreads();
        // ================= layer 1: z = w1i*h0 + w1h*h1 =================
#pragma unroll
        for (int p = 0; p < 4; p++) {
            float a[4] = {0.f, 0.f, 0.f, 0.f};
            const uint4* wi_c = wpk + (((1 * 4 + p) * 512 + tid) << 2);
            const uint4* wh_c = wpk + (((2 * 4 + p) * 512 + tid) << 2);
#pragma unroll
            for (int q = 0; q < 4; q++) {
                uint4 wi4 = wi_c[q], wh4 = wh_c[q];
#pragma unroll
                for (int b = 0; b < 4; b++) {
                    uint4 vi = VEC_CHUNK(0, b, q);
                    uint4 vh = VEC_CHUNK(1, b, q);
                    a[b] = FDOT2(u2h(wi4.x), u2h(vi.x), a[b]);
                    a[b] = FDOT2(u2h(wi4.y), u2h(vi.y), a[b]);
                    a[b] = FDOT2(u2h(wi4.z), u2h(vi.z), a[b]);
                    a[b] = FDOT2(u2h(wi4.w), u2h(vi.w), a[b]);
                    a[b] = FDOT2(u2h(wh4.x), u2h(vh.x), a[b]);
                    a[b] = FDOT2(u2h(wh4.y), u2h(vh.y), a[b]);
                    a[b] = FDOT2(u2h(wh4.z), u2h(vh.z), a[b]);
                    a[b] = FDOT2(u2h(wh4.w), u2h(vh.w), a[b]);
                }
            }
#pragma unroll
            for (int b = 0; b < 4; b++) {
                a[b] += __shfl_xor(a[b], 1);
                a[b] += __shfl_xor(a[b], 2);
            }
            if (g == 0) {
#pragma unroll
                for (int b = 0; b < 4; b++) z_s[b][p * 128 + r] = a[b] + bs1[p];
            }
        }
        __syncthreads();
        {
            float zi = z_s[bb][jh], zf = z_s[bb][HH + jh], zg = z_s[bb][2 * HH + jh], zo = z_s[bb][3 * HH + jh];
            c1 = sigm(zf) * c1 + sigm(zi) * tanhf_(zg);
            float h = sigm(zo) * tanhf_(c1);
            h_h[1][bb][jh] = f2h(h);
        }
        __syncthreads();
        // ================= layer 2: z = w2i*h1 + w2h*h2 =================
#pragma unroll
        for (int p = 0; p < 4; p++) {
            float a[4] = {0.f, 0.f, 0.f, 0.f};
            const uint4* wi_c = wpk + (((3 * 4 + p) * 512 + tid) << 2);
            const uint4* wh_c = wpk + (((4 * 4 + p) * 512 + tid) << 2);
#pragma unroll
            for (int q = 0; q < 4; q++) {
                uint4 wi4 = wi_c[q], wh4 = wh_c[q];
#pragma unroll
                for (int b = 0; b < 4; b++) {
                    uint4 vi = VEC_CHUNK(1, b, q);
                    uint4 vh = VEC_CHUNK(2, b, q);
                    a[b] = FDOT2(u2h(wi4.x), u2h(vi.x), a[b]);
                    a[b] = FDOT2(u2h(wi4.y), u2h(vi.y), a[b]);
                    a[b] = FDOT2(u2h(wi4.z), u2h(vi.z), a[b]);
                    a[b] = FDOT2(u2h(wi4.w), u2h(vi.w), a[b]);
                    a[b] = FDOT2(u2h(wh4.x), u2h(vh.x), a[b]);
                    a[b] = FDOT2(u2h(wh4.y), u2h(vh.y), a[b]);
                    a[b] = FDOT2(u2h(wh4.z), u2h(vh.z), a[b]);
                    a[b] = FDOT2(u2h(wh4.w), u2h(vh.w), a[b]);
                }
            }
#pragma unroll
            for (int b = 0; b < 4; b++) {
                a[b] += __shfl_xor(a[b], 1);
                a[b] += __shfl_xor(a[b], 2);
            }
            if (g == 0) {
#pragma unroll
                for (int b = 0; b < 4; b++) z_s[b][p * 128 + r] = a[b] + bs2[p];
            }
        }
        __syncthreads();
        {
            float zi = z_s[bb][jh], zf = z_s[bb][HH + jh], zg = z_s[bb][2 * HH + jh], zo = z_s[bb][3 * HH + jh];
            c2 = sigm(zf) * c2 + sigm(zi) * tanhf_(zg);
            float h = sigm(zo) * tanhf_(c2);
            h_h[2][bb][jh] = f2h(h);
            h2f_s[bb][jh] = h;
        }
        __syncthreads();
        // ----- fc + feedback -----
        if (tid < 256) {
            const int w = tid >> 6, lane = tid & 63;
            float p = h2f_s[w][lane] * fcw_s[lane] + h2f_s[w][lane + 64] * fcw_s[lane + 64];
#pragma unroll
            for (int off = 32; off > 0; off >>= 1) p += __shfl_down(p, off);
            if (lane == 0) {
                float pr = p + fcbv;
                out[(size_t)(b0 + w) * NPRED + s] = pr;
                in0_s[w][0] = pr;
            }
        } else if (tid < 272) {
            int q = tid - 256;            // 0..15
            int b = q >> 2, k = q & 3;
            if (k > 0) in0_s[b][k] = 0.f; // zeros_feat
        }
        __syncthreads();
    }
#undef VEC_CHUNK
}

extern "C" void kernel_launch(void* const* d_in, const int* in_sizes, int n_in,
                              void* d_out, int out_size, void* d_ws, size_t ws_size,
                              hipStream_t stream)
{
    const float* x = (const float*)d_in[0];
    const float* e0_wih = (const float*)d_in[1];
    const float* e0_whh = (const float*)d_in[2];
    const float* e0_bih = (const float*)d_in[3];
    const float* e0_bhh = (const float*)d_in[4];
    const float* e1_wih = (const float*)d_in[5];
    const float* e1_whh = (const float*)d_in[6];
    const float* e1_bih = (const float*)d_in[7];
    const float* e1_bhh = (const float*)d_in[8];
    const float* e2_wih = (const float*)d_in[9];
    const float* e2_whh = (const float*)d_in[10];
    const float* e2_bih = (const float*)d_in[11];
    const float* e2_bhh = (const float*)d_in[12];
    const float* d0_wih = (const float*)d_in[13];
    const float* d0_whh = (const float*)d_in[14];
    const float* d0_bih = (const float*)d_in[15];
    const float* d0_bhh = (const float*)d_in[16];
    const float* d1_wih = (const float*)d_in[17];
    const float* d1_whh = (const float*)d_in[18];
    const float* d1_bih = (const float*)d_in[19];
    const float* d1_bhh = (const float*)d_in[20];
    const float* d2_wih = (const float*)d_in[21];
    const float* d2_whh = (const float*)d_in[22];
    const float* d2_bih = (const float*)d_in[23];
    const float* d2_bhh = (const float*)d_in[24];
    const float* fc_w = (const float*)d_in[25];
    const float* fc_b = (const float*)d_in[26];

    // workspace layout
    u16* ys = (u16*)d_ws;                                   // B*T*H bf16 = 33.5 MB
    size_t ys_bytes = (size_t)BB * TT * HH * sizeof(u16);
    float* hst = (float*)((char*)d_ws + ys_bytes);          // 3*B*H f32
    float* cst = hst + (size_t)3 * BB * HH;                 // 3*B*H f32
    u32* wpk = (u32*)(cst + (size_t)3 * BB * HH);           // 163840 u32 = 640 KB
    const size_t BH = (size_t)BB * HH;

    k_pack<<<dim3(640), dim3(256), 0, stream>>>(d0_whh, d1_wih, d1_whh, d2_wih, d2_whh, wpk);
    k_scan0<<<dim3(256), dim3(1024), 0, stream>>>(x, e0_wih, e0_whh, e0_bih, e0_bhh,
                                                  ys, hst, cst);
    k_scanL<<<dim3(256), dim3(1024), 0, stream>>>(e1_wih, e1_whh, e1_bih, e1_bhh,
                                                  ys, 1, hst + BH, cst + BH);
    k_scanL<<<dim3(256), dim3(1024), 0, stream>>>(e2_wih, e2_whh, e2_bih, e2_bhh,
                                                  ys, 0, hst + 2 * BH, cst + 2 * BH);
    k_decode<<<dim3(128), dim3(512), 0, stream>>>(
        x, d0_wih, d0_bih, d0_bhh, d1_bih, d1_bhh, d2_bih, d2_bhh,
        fc_w, fc_b, hst, cst, (const uint4*)wpk, (float*)d_out);
}

// Round 10
// 2647.133 us; speedup vs baseline: 6.1141x; 1.0580x over previous
//
#include <hip/hip_runtime.h>
#include <hip/hip_bf16.h>

#define HH 128     // hidden
#define G4 512     // 4*H
#define TT 256     // encoder timesteps
#define BB 512     // batch
#define NPRED 50   // decoder steps

typedef unsigned short u16;
typedef unsigned int u32;
typedef _Float16 h2_t __attribute__((ext_vector_type(2)));

__device__ __forceinline__ float sigm(float x) { return 1.0f / (1.0f + __expf(-x)); }
__device__ __forceinline__ float tanhf_(float x) { return 1.0f - 2.0f / (__expf(2.0f * x) + 1.0f); }
__device__ __forceinline__ float bf2f(u16 u) { return __uint_as_float(((u32)u) << 16); }
__device__ __forceinline__ u16 f2bf(float f) {
    u32 x = __float_as_uint(f);
    u32 r = (x + 0x7fffu + ((x >> 16) & 1u)) >> 16;   // RTNE
    return (u16)r;
}
__device__ __forceinline__ u32 pkh2(float a, float b) {
    u16 lo = __builtin_bit_cast(u16, (_Float16)a);
    u16 hi = __builtin_bit_cast(u16, (_Float16)b);
    return (u32)lo | ((u32)hi << 16);
}
__device__ __forceinline__ h2_t u2h(u32 u) { return __builtin_bit_cast(h2_t, u); }
__device__ __forceinline__ u16 f2h(float f) { return __builtin_bit_cast(u16, (_Float16)f); }

#if defined(__has_builtin)
#if __has_builtin(__builtin_amdgcn_fdot2)
#define HAVE_FDOT2 1
#endif
#endif
#ifdef HAVE_FDOT2
#define FDOT2(w, v, acc) __builtin_amdgcn_fdot2((w), (v), (acc), false)
#else
__device__ __forceinline__ float FDOT2(h2_t a, h2_t b, float c) {
    return c + (float)a.x * (float)b.x + (float)a.y * (float)b.y;
}
#endif

// ---------------------------------------------------------------------------
// Encoder layer 0 (unchanged from round 9 — measured: VGPR 48, 0 bank
// conflicts). 1024 thr, 2 batch el/block, grid 256.
// ---------------------------------------------------------------------------
__global__ void __launch_bounds__(1024) k_scan0(
    const float* __restrict__ x, const float* __restrict__ wih,
    const float* __restrict__ whh, const float* __restrict__ bih,
    const float* __restrict__ bhh, u16* __restrict__ ys,
    float* __restrict__ hst, float* __restrict__ cst)
{
    const int tid = threadIdx.x;
    const int row = tid >> 1, half = tid & 1, base = half * 64;
    const int b0 = blockIdx.x * 2;
    __shared__ __align__(16) u16  h_h[2][HH];    // f16 hidden state
    __shared__ __align__(16) float z_s[2][G4];
    __shared__ float x_s[2][4];

    u32 wph[32];   // whh[row][base..base+64) as 32 f16-pairs
    {
        const float2* wrow = reinterpret_cast<const float2*>(whh + (size_t)row * HH + base);
#pragma unroll
        for (int k2 = 0; k2 < 32; k2++) {
            float2 v = wrow[k2];
            wph[k2] = pkh2(v.x, v.y);
        }
    }
    float wi0 = 0.f, wi1 = 0.f, wi2 = 0.f, wi3 = 0.f, bias = 0.f;
    if (half == 0) {
        wi0 = wih[row * 4]; wi1 = wih[row * 4 + 1]; wi2 = wih[row * 4 + 2]; wi3 = wih[row * 4 + 3];
        bias = bih[row] + bhh[row];
    }
    const int bb = tid >> 7, jh = tid & 127;   // eltwise roles (tid < 256)
    float creg = 0.f, hreg = 0.f;

    if (tid < 256) h_h[bb][jh] = 0;
    if (tid < 8) x_s[tid >> 2][tid & 3] = x[(size_t)(b0 + (tid >> 2)) * TT * 4 + (tid & 3)];
    __syncthreads();

    for (int t = 0; t < TT; t++) {
        float xnext = 0.f;
        if (tid < 8 && t + 1 < TT)
            xnext = x[(size_t)(b0 + (tid >> 2)) * TT * 4 + (size_t)(t + 1) * 4 + (tid & 3)];

        float a0 = 0.f, a1 = 0.f;
        if (half == 0) {
            a0 = bias + wi0 * x_s[0][0] + wi1 * x_s[0][1] + wi2 * x_s[0][2] + wi3 * x_s[0][3];
            a1 = bias + wi0 * x_s[1][0] + wi1 * x_s[1][1] + wi2 * x_s[1][2] + wi3 * x_s[1][3];
        }
#pragma unroll
        for (int q = 0; q < 8; q++) {
            uint4 hq0 = *reinterpret_cast<const uint4*>(
                reinterpret_cast<const char*>(h_h[0]) + base * 2 + q * 16);
            uint4 hq1 = *reinterpret_cast<const uint4*>(
                reinterpret_cast<const char*>(h_h[1]) + base * 2 + q * 16);
            u32 w0 = wph[4 * q], w1 = wph[4 * q + 1], w2 = wph[4 * q + 2], w3 = wph[4 * q + 3];
            a0 = FDOT2(u2h(w0), u2h(hq0.x), a0);
            a0 = FDOT2(u2h(w1), u2h(hq0.y), a0);
            a0 = FDOT2(u2h(w2), u2h(hq0.z), a0);
            a0 = FDOT2(u2h(w3), u2h(hq0.w), a0);
            a1 = FDOT2(u2h(w0), u2h(hq1.x), a1);
            a1 = FDOT2(u2h(w1), u2h(hq1.y), a1);
            a1 = FDOT2(u2h(w2), u2h(hq1.z), a1);
            a1 = FDOT2(u2h(w3), u2h(hq1.w), a1);
        }
        a0 += __shfl_xor(a0, 1);
        a1 += __shfl_xor(a1, 1);
        if (half == 0) { z_s[0][row] = a0; z_s[1][row] = a1; }
        __syncthreads();

        if (tid < 256) {
            float zi = z_s[bb][jh], zf = z_s[bb][HH + jh], zg = z_s[bb][2 * HH + jh], zo = z_s[bb][3 * HH + jh];
            float c = sigm(zf) * creg + sigm(zi) * tanhf_(zg);
            float h = sigm(zo) * tanhf_(c);
            creg = c; hreg = h;
            h_h[bb][jh] = f2h(h);
            ys[((size_t)(b0 + bb) * TT + t) * HH + jh] = f2bf(h);
        }
        if (tid < 8 && t + 1 < TT) x_s[tid >> 2][tid & 3] = xnext;
        __syncthreads();
    }
    if (tid < 256) {
        hst[(size_t)(b0 + bb) * HH + jh] = hreg;
        cst[(size_t)(b0 + bb) * HH + jh] = creg;
    }
}

// ---------------------------------------------------------------------------
// Encoder layers 1,2 (unchanged from round 9 — measured-good).
// ---------------------------------------------------------------------------
__global__ void __launch_bounds__(1024) k_scanL(
    const float* __restrict__ wih, const float* __restrict__ whh,
    const float* __restrict__ bih, const float* __restrict__ bhh,
    u16* __restrict__ ys, int write_ys,
    float* __restrict__ hst, float* __restrict__ cst)
{
    const int tid = threadIdx.x;
    const int row = tid >> 1, half = tid & 1, base = half * 64;
    const int b0 = blockIdx.x * 2;
    __shared__ __align__(16) u16  h_h[2][HH];    // f16 hidden
    __shared__ __align__(16) u16  y_h[2][HH];    // f16 layer input
    __shared__ __align__(16) float z_s[2][G4];

    u32 wph[32], wpi[32];
    {
        const float2* wrow = reinterpret_cast<const float2*>(whh + (size_t)row * HH + base);
        const float2* irow = reinterpret_cast<const float2*>(wih + (size_t)row * HH + base);
#pragma unroll
        for (int k2 = 0; k2 < 32; k2++) {
            float2 v = wrow[k2]; wph[k2] = pkh2(v.x, v.y);
            float2 w = irow[k2]; wpi[k2] = pkh2(w.x, w.y);
        }
    }
    const float bias = bih[row] + bhh[row];   // used by half==0 at write
    const int bb = tid >> 7, jh = tid & 127;
    float creg = 0.f, hreg = 0.f;

    if (tid < 256) {
        h_h[bb][jh] = 0;
        y_h[bb][jh] = f2h(bf2f(ys[((size_t)(b0 + bb) * TT) * HH + jh]));
    }
    __syncthreads();

    for (int t = 0; t < TT; t++) {
        u16 ynext = 0;
        if (tid < 256 && t + 1 < TT)
            ynext = ys[((size_t)(b0 + bb) * TT + (t + 1)) * HH + jh];

        float a0 = 0.f, a1 = 0.f;
#pragma unroll
        for (int q = 0; q < 8; q++) {
            uint4 hq0 = *reinterpret_cast<const uint4*>(
                reinterpret_cast<const char*>(h_h[0]) + base * 2 + q * 16);
            uint4 hq1 = *reinterpret_cast<const uint4*>(
                reinterpret_cast<const char*>(h_h[1]) + base * 2 + q * 16);
            uint4 yq0 = *reinterpret_cast<const uint4*>(
                reinterpret_cast<const char*>(y_h[0]) + base * 2 + q * 16);
            uint4 yq1 = *reinterpret_cast<const uint4*>(
                reinterpret_cast<const char*>(y_h[1]) + base * 2 + q * 16);
            u32 h0 = wph[4 * q], h1 = wph[4 * q + 1], h2 = wph[4 * q + 2], h3 = wph[4 * q + 3];
            u32 i0 = wpi[4 * q], i1 = wpi[4 * q + 1], i2 = wpi[4 * q + 2], i3 = wpi[4 * q + 3];
            a0 = FDOT2(u2h(h0), u2h(hq0.x), a0);
            a0 = FDOT2(u2h(h1), u2h(hq0.y), a0);
            a0 = FDOT2(u2h(h2), u2h(hq0.z), a0);
            a0 = FDOT2(u2h(h3), u2h(hq0.w), a0);
            a0 = FDOT2(u2h(i0), u2h(yq0.x), a0);
            a0 = FDOT2(u2h(i1), u2h(yq0.y), a0);
            a0 = FDOT2(u2h(i2), u2h(yq0.z), a0);
            a0 = FDOT2(u2h(i3), u2h(yq0.w), a0);
            a1 = FDOT2(u2h(h0), u2h(hq1.x), a1);
            a1 = FDOT2(u2h(h1), u2h(hq1.y), a1);
            a1 = FDOT2(u2h(h2), u2h(hq1.z), a1);
            a1 = FDOT2(u2h(h3), u2h(hq1.w), a1);
            a1 = FDOT2(u2h(i0), u2h(yq1.x), a1);
            a1 = FDOT2(u2h(i1), u2h(yq1.y), a1);
            a1 = FDOT2(u2h(i2), u2h(yq1.z), a1);
            a1 = FDOT2(u2h(i3), u2h(yq1.w), a1);
        }
        a0 += __shfl_xor(a0, 1);
        a1 += __shfl_xor(a1, 1);
        if (half == 0) { z_s[0][row] = a0 + bias; z_s[1][row] = a1 + bias; }
        __syncthreads();

        if (tid < 256) {
            float zi = z_s[bb][jh], zf = z_s[bb][HH + jh], zg = z_s[bb][2 * HH + jh], zo = z_s[bb][3 * HH + jh];
            float c = sigm(zf) * creg + sigm(zi) * tanhf_(zg);
            float h = sigm(zo) * tanhf_(c);
            creg = c; hreg = h;
            h_h[bb][jh] = f2h(h);
            if (write_ys) ys[((size_t)(b0 + bb) * TT + t) * HH + jh] = f2bf(h);
            if (t + 1 < TT) y_h[bb][jh] = f2h(bf2f(ynext));
        }
        __syncthreads();
    }
    if (tid < 256) {
        hst[(size_t)(b0 + bb) * HH + jh] = hreg;
        cst[(size_t)(b0 + bb) * HH + jh] = creg;
    }
}

// ---------------------------------------------------------------------------
// Pack the 5 decoder 512x128 matrices (w0h,w1i,w1h,w2i,w2h) to f16 pairs in
// the 1024-thread 8-lane-per-row decode order: u32 index
// o = ((m*4+p)*1024 + t)*8 + u ; row = p*128 + (t>>3); col = (t&7)*16 + 2u.
// ---------------------------------------------------------------------------
__global__ void __launch_bounds__(256) k_pack(
    const float* __restrict__ w0h, const float* __restrict__ w1i,
    const float* __restrict__ w1h, const float* __restrict__ w2i,
    const float* __restrict__ w2h, u32* __restrict__ wpk)
{
    int o = blockIdx.x * 256 + threadIdx.x;      // 0 .. 163839
    int m = o >> 15;            // 32768 u32 per matrix
    int rem = o & 32767;
    int p = rem >> 13;          // 8192 u32 per gate-block
    int rem2 = rem & 8191;
    int t = rem2 >> 3;          // thread 0..1023
    int u = rem2 & 7;           // u32 within thread's 2 uint4
    int row = p * 128 + (t >> 3);
    int col = (t & 7) * 16 + 2 * u;
    const float* src = (m == 0) ? w0h : (m == 1) ? w1i : (m == 2) ? w1h : (m == 3) ? w2i : w2h;
    float v0 = src[row * 128 + col], v1 = src[row * 128 + col + 1];
    wpk[o] = pkh2(v0, v1);
}

// ---------------------------------------------------------------------------
// Decoder: 50 steps x 3 layers. 1024 thr, 4 batch, grid 128 (16 waves/CU).
// 8 lanes per output row (g=tid&7, 16 cols each): per-thread weight loads
// per step drop 80 -> 40 uint4, halving the live-range pressure that made
// the 512-thread version spill at the 128-VGPR cap (round 6/9: FETCH 1.08 GB
// + WRITE 123 MB of scratch reload, 29 us/step). Biases/wi0 staged in LDS
// (frees 28 persistent regs). 3-level shfl_xor reduce (1,2,4 — same wave).
// ---------------------------------------------------------------------------
__global__ void __launch_bounds__(1024) k_decode(
    const float* __restrict__ x,
    const float* __restrict__ w0i,
    const float* __restrict__ b0i, const float* __restrict__ b0h,
    const float* __restrict__ b1i, const float* __restrict__ b1h,
    const float* __restrict__ b2i, const float* __restrict__ b2h,
    const float* __restrict__ fcw, const float* __restrict__ fcb,
    const float* __restrict__ hst, const float* __restrict__ cst,
    const uint4* __restrict__ wpk,
    float* __restrict__ out)
{
    const int tid = threadIdx.x;
    const int b0 = blockIdx.x * 4;
    const int r = tid >> 3;        // output row slot 0..127
    const int g = tid & 7;         // 16-col group
    __shared__ __align__(16) u16  h_h[3][4][HH];     // f16 hidden states
    __shared__ __align__(16) float h2f_s[4][HH];     // f32 copy of layer-2 h (fc)
    __shared__ __align__(16) float z_s[4][G4];
    __shared__ __align__(16) float in0_s[4][4];
    __shared__ __align__(16) float fcw_s[HH];
    __shared__ __align__(16) float bs_lds[3][G4];    // bih+bhh per layer
    __shared__ __align__(16) float wi0_lds[G4][4];   // layer-0 wih rows

    const int bb = tid >> 7, jh = tid & 127;         // eltwise roles (tid<512)
    float c0 = 0.f, c1 = 0.f, c2 = 0.f;
    if (tid < 512) {
        c0 = cst[((size_t)0 * BB + b0 + bb) * HH + jh];
        c1 = cst[((size_t)1 * BB + b0 + bb) * HH + jh];
        c2 = cst[((size_t)2 * BB + b0 + bb) * HH + jh];
        h_h[0][bb][jh] = f2h(hst[((size_t)0 * BB + b0 + bb) * HH + jh]);
        h_h[1][bb][jh] = f2h(hst[((size_t)1 * BB + b0 + bb) * HH + jh]);
        h_h[2][bb][jh] = f2h(hst[((size_t)2 * BB + b0 + bb) * HH + jh]);
        bs_lds[0][tid] = b0i[tid] + b0h[tid];
        bs_lds[1][tid] = b1i[tid] + b1h[tid];
        bs_lds[2][tid] = b2i[tid] + b2h[tid];
        float4 wv = reinterpret_cast<const float4*>(w0i)[tid];
        wi0_lds[tid][0] = wv.x; wi0_lds[tid][1] = wv.y;
        wi0_lds[tid][2] = wv.z; wi0_lds[tid][3] = wv.w;
    }
    if (tid < HH) fcw_s[tid] = fcw[tid];
    if (tid < 16) in0_s[tid >> 2][tid & 3] = x[(size_t)(b0 + (tid >> 2)) * TT * 4 + (size_t)(TT - 1) * 4 + (tid & 3)];
    const float fcbv = fcb[0];
    __syncthreads();

#define VEC_CHUNK(l, b, q) (*reinterpret_cast<const uint4*>( \
        reinterpret_cast<const char*>(&h_h[l][b][0]) + g * 32 + (q) * 16))

    for (int s = 0; s < NPRED; s++) {
        // ================= layer 0: z = w0i*in0 + w0h*h0 =================
#pragma unroll
        for (int p = 0; p < 4; p++) {
            float a[4] = {0.f, 0.f, 0.f, 0.f};
            const uint4* wh_c = wpk + (((0 * 4 + p) * 1024 + tid) << 1);
#pragma unroll
            for (int q = 0; q < 2; q++) {
                uint4 w4 = wh_c[q];
#pragma unroll
                for (int b = 0; b < 4; b++) {
                    uint4 v = VEC_CHUNK(0, b, q);
                    a[b] = FDOT2(u2h(w4.x), u2h(v.x), a[b]);
                    a[b] = FDOT2(u2h(w4.y), u2h(v.y), a[b]);
                    a[b] = FDOT2(u2h(w4.z), u2h(v.z), a[b]);
                    a[b] = FDOT2(u2h(w4.w), u2h(v.w), a[b]);
                }
            }
#pragma unroll
            for (int b = 0; b < 4; b++) {
                a[b] += __shfl_xor(a[b], 1);
                a[b] += __shfl_xor(a[b], 2);
                a[b] += __shfl_xor(a[b], 4);
            }
            if (g == 0) {
                int row = p * 128 + r;
                float w0 = wi0_lds[row][0], w1 = wi0_lds[row][1];
                float w2 = wi0_lds[row][2], w3 = wi0_lds[row][3];
                float bs = bs_lds[0][row];
#pragma unroll
                for (int b = 0; b < 4; b++) {
                    float wi = w0 * in0_s[b][0] + w1 * in0_s[b][1]
                             + w2 * in0_s[b][2] + w3 * in0_s[b][3];
                    z_s[b][row] = a[b] + bs + wi;
                }
            }
        }
        __syncthreads();
        if (tid < 512) {
            float zi = z_s[bb][jh], zf = z_s[bb][HH + jh], zg = z_s[bb][2 * HH + jh], zo = z_s[bb][3 * HH + jh];
            c0 = sigm(zf) * c0 + sigm(zi) * tanhf_(zg);
            float h = sigm(zo) * tanhf_(c0);
            h_h[0][bb][jh] = f2h(h);
        }
        __syncthreads();
        // ================= layer 1: z = w1i*h0 + w1h*h1 =================
#pragma unroll
        for (int p = 0; p < 4; p++) {
            float a[4] = {0.f, 0.f, 0.f, 0.f};
            const uint4* wi_c = wpk + (((1 * 4 + p) * 1024 + tid) << 1);
            const uint4* wh_c = wpk + (((2 * 4 + p) * 1024 + tid) << 1);
#pragma unroll
            for (int q = 0; q < 2; q++) {
                uint4 wi4 = wi_c[q], wh4 = wh_c[q];
#pragma unroll
                for (int b = 0; b < 4; b++) {
                    uint4 vi = VEC_CHUNK(0, b, q);
                    uint4 vh = VEC_CHUNK(1, b, q);
                    a[b] = FDOT2(u2h(wi4.x), u2h(vi.x), a[b]);
                    a[b] = FDOT2(u2h(wi4.y), u2h(vi.y), a[b]);
                    a[b] = FDOT2(u2h(wi4.z), u2h(vi.z), a[b]);
                    a[b] = FDOT2(u2h(wi4.w), u2h(vi.w), a[b]);
                    a[b] = FDOT2(u2h(wh4.x), u2h(vh.x), a[b]);
                    a[b] = FDOT2(u2h(wh4.y), u2h(vh.y), a[b]);
                    a[b] = FDOT2(u2h(wh4.z), u2h(vh.z), a[b]);
                    a[b] = FDOT2(u2h(wh4.w), u2h(vh.w), a[b]);
                }
            }
#pragma unroll
            for (int b = 0; b < 4; b++) {
                a[b] += __shfl_xor(a[b], 1);
                a[b] += __shfl_xor(a[b], 2);
                a[b] += __shfl_xor(a[b], 4);
            }
            if (g == 0) {
                int row = p * 128 + r;
                float bs = bs_lds[1][row];
#pragma unroll
                for (int b = 0; b < 4; b++) z_s[b][row] = a[b] + bs;
            }
        }
        __syncthreads();
        if (tid < 512) {
            float zi = z_s[bb][jh], zf = z_s[bb][HH + jh], zg = z_s[bb][2 * HH + jh], zo = z_s[bb][3 * HH + jh];
            c1 = sigm(zf) * c1 + sigm(zi) * tanhf_(zg);
            float h = sigm(zo) * tanhf_(c1);
            h_h[1][bb][jh] = f2h(h);
        }
        __syncthreads();
        // ================= layer 2: z = w2i*h1 + w2h*h2 =================
#pragma unroll
        for (int p = 0; p < 4; p++) {
            float a[4] = {0.f, 0.f, 0.f, 0.f};
            const uint4* wi_c = wpk + (((3 * 4 + p) * 1024 + tid) << 1);
            const uint4* wh_c = wpk + (((4 * 4 + p) * 1024 + tid) << 1);
#pragma unroll
            for (int q = 0; q < 2; q++) {
                uint4 wi4 = wi_c[q], wh4 = wh_c[q];
#pragma unroll
                for (int b = 0; b < 4; b++) {
                    uint4 vi = VEC_CHUNK(1, b, q);
                    uint4 vh = VEC_CHUNK(2, b, q);
                    a[b] = FDOT2(u2h(wi4.x), u2h(vi.x), a[b]);
                    a[b] = FDOT2(u2h(wi4.y), u2h(vi.y), a[b]);
                    a[b] = FDOT2(u2h(wi4.z), u2h(vi.z), a[b]);
                    a[b] = FDOT2(u2h(wi4.w), u2h(vi.w), a[b]);
                    a[b] = FDOT2(u2h(wh4.x), u2h(vh.x), a[b]);
                    a[b] = FDOT2(u2h(wh4.y), u2h(vh.y), a[b]);
                    a[b] = FDOT2(u2h(wh4.z), u2h(vh.z), a[b]);
                    a[b] = FDOT2(u2h(wh4.w), u2h(vh.w), a[b]);
                }
            }
#pragma unroll
            for (int b = 0; b < 4; b++) {
                a[b] += __shfl_xor(a[b], 1);
                a[b] += __shfl_xor(a[b], 2);
                a[b] += __shfl_xor(a[b], 4);
            }
            if (g == 0) {
                int row = p * 128 + r;
                float bs = bs_lds[2][row];
#pragma unroll
                for (int b = 0; b < 4; b++) z_s[b][row] = a[b] + bs;
            }
        }
        __syncthreads();
        if (tid < 512) {
            float zi = z_s[bb][jh], zf = z_s[bb][HH + jh], zg = z_s[bb][2 * HH + jh], zo = z_s[bb][3 * HH + jh];
            c2 = sigm(zf) * c2 + sigm(zi) * tanhf_(zg);
            float h = sigm(zo) * tanhf_(c2);
            h_h[2][bb][jh] = f2h(h);
            h2f_s[bb][jh] = h;
        }
        __syncthreads();
        // ----- fc + feedback -----
        if (tid < 256) {
            const int w = tid >> 6, lane = tid & 63;
            float p = h2f_s[w][lane] * fcw_s[lane] + h2f_s[w][lane + 64] * fcw_s[lane + 64];
#pragma unroll
            for (int off = 32; off > 0; off >>= 1) p += __shfl_down(p, off);
            if (lane == 0) {
                float pr = p + fcbv;
                out[(size_t)(b0 + w) * NPRED + s] = pr;
                in0_s[w][0] = pr;
            }
        } else if (tid < 272) {
            int q = tid - 256;            // 0..15
            int b = q >> 2, k = q & 3;
            if (k > 0) in0_s[b][k] = 0.f; // zeros_feat
        }
        __syncthreads();
    }
#undef VEC_CHUNK
}

extern "C" void kernel_launch(void* const* d_in, const int* in_sizes, int n_in,
                              void* d_out, int out_size, void* d_ws, size_t ws_size,
                              hipStream_t stream)
{
    const float* x = (const float*)d_in[0];
    const float* e0_wih = (const float*)d_in[1];
    const float* e0_whh = (const float*)d_in[2];
    const float* e0_bih = (const float*)d_in[3];
    const float* e0_bhh = (const float*)d_in[4];
    const float* e1_wih = (const float*)d_in[5];
    const float* e1_whh = (const float*)d_in[6];
    const float* e1_bih = (const float*)d_in[7];
    const float* e1_bhh = (const float*)d_in[8];
    const float* e2_wih = (const float*)d_in[9];
    const float* e2_whh = (const float*)d_in[10];
    const float* e2_bih = (const float*)d_in[11];
    const float* e2_bhh = (const float*)d_in[12];
    const float* d0_wih = (const float*)d_in[13];
    const float* d0_whh = (const float*)d_in[14];
    const float* d0_bih = (const float*)d_in[15];
    const float* d0_bhh = (const float*)d_in[16];
    const float* d1_wih = (const float*)d_in[17];
    const float* d1_whh = (const float*)d_in[18];
    const float* d1_bih = (const float*)d_in[19];
    const float* d1_bhh = (const float*)d_in[20];
    const float* d2_wih = (const float*)d_in[21];
    const float* d2_whh = (const float*)d_in[22];
    const float* d2_bih = (const float*)d_in[23];
    const float* d2_bhh = (const float*)d_in[24];
    const float* fc_w = (const float*)d_in[25];
    const float* fc_b = (const float*)d_in[26];

    // workspace layout
    u16* ys = (u16*)d_ws;                                   // B*T*H bf16 = 33.5 MB
    size_t ys_bytes = (size_t)BB * TT * HH * sizeof(u16);
    float* hst = (float*)((char*)d_ws + ys_bytes);          // 3*B*H f32
    float* cst = hst + (size_t)3 * BB * HH;                 // 3*B*H f32
    u32* wpk = (u32*)(cst + (size_t)3 * BB * HH);           // 163840 u32 = 640 KB
    const size_t BH = (size_t)BB * HH;

    k_pack<<<dim3(640), dim3(256), 0, stream>>>(d0_whh, d1_wih, d1_whh, d2_wih, d2_whh, wpk);
    k_scan0<<<dim3(256), dim3(1024), 0, stream>>>(x, e0_wih, e0_whh, e0_bih, e0_bhh,
                                                  ys, hst, cst);
    k_scanL<<<dim3(256), dim3(1024), 0, stream>>>(e1_wih, e1_whh, e1_bih, e1_bhh,
                                                  ys, 1, hst + BH, cst + BH);
    k_scanL<<<dim3(256), dim3(1024), 0, stream>>>(e2_wih, e2_whh, e2_bih, e2_bhh,
                                                  ys, 0, hst + 2 * BH, cst + 2 * BH);
    k_decode<<<dim3(128), dim3(1024), 0, stream>>>(
        x, d0_wih, d0_bih, d0_bhh, d1_bih, d1_bhh, d2_bih, d2_bhh,
        fc_w, fc_b, hst, cst, (const uint4*)wpk, (float*)d_out);
}

// Round 11
// 2562.300 us; speedup vs baseline: 6.3166x; 1.0331x over previous
//
#include <hip/hip_runtime.h>
#include <hip/hip_bf16.h>

#define HH 128     // hidden
#define G4 512     // 4*H
#define TT 256     // encoder timesteps
#define BB 512     // batch
#define NPRED 50   // decoder steps

typedef unsigned short u16;
typedef unsigned int u32;
typedef _Float16 h2_t __attribute__((ext_vector_type(2)));

__device__ __forceinline__ float sigm(float x) { return 1.0f / (1.0f + __expf(-x)); }
__device__ __forceinline__ float tanhf_(float x) { return 1.0f - 2.0f / (__expf(2.0f * x) + 1.0f); }
__device__ __forceinline__ float bf2f(u16 u) { return __uint_as_float(((u32)u) << 16); }
__device__ __forceinline__ u16 f2bf(float f) {
    u32 x = __float_as_uint(f);
    u32 r = (x + 0x7fffu + ((x >> 16) & 1u)) >> 16;   // RTNE
    return (u16)r;
}
__device__ __forceinline__ u32 pkh2(float a, float b) {
    u16 lo = __builtin_bit_cast(u16, (_Float16)a);
    u16 hi = __builtin_bit_cast(u16, (_Float16)b);
    return (u32)lo | ((u32)hi << 16);
}
__device__ __forceinline__ h2_t u2h(u32 u) { return __builtin_bit_cast(h2_t, u); }
__device__ __forceinline__ u16 f2h(float f) { return __builtin_bit_cast(u16, (_Float16)f); }

#if defined(__has_builtin)
#if __has_builtin(__builtin_amdgcn_fdot2)
#define HAVE_FDOT2 1
#endif
#endif
#ifdef HAVE_FDOT2
#define FDOT2(w, v, acc) __builtin_amdgcn_fdot2((w), (v), (acc), false)
#else
__device__ __forceinline__ float FDOT2(h2_t a, h2_t b, float c) {
    return c + (float)a.x * (float)b.x + (float)a.y * (float)b.y;
}
#endif

// ---------------------------------------------------------------------------
// Encoder layer 0 (unchanged — measured: VGPR 48, 0 bank conflicts).
// ---------------------------------------------------------------------------
__global__ void __launch_bounds__(1024) k_scan0(
    const float* __restrict__ x, const float* __restrict__ wih,
    const float* __restrict__ whh, const float* __restrict__ bih,
    const float* __restrict__ bhh, u16* __restrict__ ys,
    float* __restrict__ hst, float* __restrict__ cst)
{
    const int tid = threadIdx.x;
    const int row = tid >> 1, half = tid & 1, base = half * 64;
    const int b0 = blockIdx.x * 2;
    __shared__ __align__(16) u16  h_h[2][HH];    // f16 hidden state
    __shared__ __align__(16) float z_s[2][G4];
    __shared__ float x_s[2][4];

    u32 wph[32];   // whh[row][base..base+64) as 32 f16-pairs
    {
        const float2* wrow = reinterpret_cast<const float2*>(whh + (size_t)row * HH + base);
#pragma unroll
        for (int k2 = 0; k2 < 32; k2++) {
            float2 v = wrow[k2];
            wph[k2] = pkh2(v.x, v.y);
        }
    }
    float wi0 = 0.f, wi1 = 0.f, wi2 = 0.f, wi3 = 0.f, bias = 0.f;
    if (half == 0) {
        wi0 = wih[row * 4]; wi1 = wih[row * 4 + 1]; wi2 = wih[row * 4 + 2]; wi3 = wih[row * 4 + 3];
        bias = bih[row] + bhh[row];
    }
    const int bb = tid >> 7, jh = tid & 127;   // eltwise roles (tid < 256)
    float creg = 0.f, hreg = 0.f;

    if (tid < 256) h_h[bb][jh] = 0;
    if (tid < 8) x_s[tid >> 2][tid & 3] = x[(size_t)(b0 + (tid >> 2)) * TT * 4 + (tid & 3)];
    __syncthreads();

    for (int t = 0; t < TT; t++) {
        float xnext = 0.f;
        if (tid < 8 && t + 1 < TT)
            xnext = x[(size_t)(b0 + (tid >> 2)) * TT * 4 + (size_t)(t + 1) * 4 + (tid & 3)];

        float a0 = 0.f, a1 = 0.f;
        if (half == 0) {
            a0 = bias + wi0 * x_s[0][0] + wi1 * x_s[0][1] + wi2 * x_s[0][2] + wi3 * x_s[0][3];
            a1 = bias + wi0 * x_s[1][0] + wi1 * x_s[1][1] + wi2 * x_s[1][2] + wi3 * x_s[1][3];
        }
#pragma unroll
        for (int q = 0; q < 8; q++) {
            uint4 hq0 = *reinterpret_cast<const uint4*>(
                reinterpret_cast<const char*>(h_h[0]) + base * 2 + q * 16);
            uint4 hq1 = *reinterpret_cast<const uint4*>(
                reinterpret_cast<const char*>(h_h[1]) + base * 2 + q * 16);
            u32 w0 = wph[4 * q], w1 = wph[4 * q + 1], w2 = wph[4 * q + 2], w3 = wph[4 * q + 3];
            a0 = FDOT2(u2h(w0), u2h(hq0.x), a0);
            a0 = FDOT2(u2h(w1), u2h(hq0.y), a0);
            a0 = FDOT2(u2h(w2), u2h(hq0.z), a0);
            a0 = FDOT2(u2h(w3), u2h(hq0.w), a0);
            a1 = FDOT2(u2h(w0), u2h(hq1.x), a1);
            a1 = FDOT2(u2h(w1), u2h(hq1.y), a1);
            a1 = FDOT2(u2h(w2), u2h(hq1.z), a1);
            a1 = FDOT2(u2h(w3), u2h(hq1.w), a1);
        }
        a0 += __shfl_xor(a0, 1);
        a1 += __shfl_xor(a1, 1);
        if (half == 0) { z_s[0][row] = a0; z_s[1][row] = a1; }
        __syncthreads();

        if (tid < 256) {
            float zi = z_s[bb][jh], zf = z_s[bb][HH + jh], zg = z_s[bb][2 * HH + jh], zo = z_s[bb][3 * HH + jh];
            float c = sigm(zf) * creg + sigm(zi) * tanhf_(zg);
            float h = sigm(zo) * tanhf_(c);
            creg = c; hreg = h;
            h_h[bb][jh] = f2h(h);
            ys[((size_t)(b0 + bb) * TT + t) * HH + jh] = f2bf(h);
        }
        if (tid < 8 && t + 1 < TT) x_s[tid >> 2][tid & 3] = xnext;
        __syncthreads();
    }
    if (tid < 256) {
        hst[(size_t)(b0 + bb) * HH + jh] = hreg;
        cst[(size_t)(b0 + bb) * HH + jh] = creg;
    }
}

// ---------------------------------------------------------------------------
// Encoder layers 1,2 (unchanged — measured-good).
// ---------------------------------------------------------------------------
__global__ void __launch_bounds__(1024) k_scanL(
    const float* __restrict__ wih, const float* __restrict__ whh,
    const float* __restrict__ bih, const float* __restrict__ bhh,
    u16* __restrict__ ys, int write_ys,
    float* __restrict__ hst, float* __restrict__ cst)
{
    const int tid = threadIdx.x;
    const int row = tid >> 1, half = tid & 1, base = half * 64;
    const int b0 = blockIdx.x * 2;
    __shared__ __align__(16) u16  h_h[2][HH];    // f16 hidden
    __shared__ __align__(16) u16  y_h[2][HH];    // f16 layer input
    __shared__ __align__(16) float z_s[2][G4];

    u32 wph[32], wpi[32];
    {
        const float2* wrow = reinterpret_cast<const float2*>(whh + (size_t)row * HH + base);
        const float2* irow = reinterpret_cast<const float2*>(wih + (size_t)row * HH + base);
#pragma unroll
        for (int k2 = 0; k2 < 32; k2++) {
            float2 v = wrow[k2]; wph[k2] = pkh2(v.x, v.y);
            float2 w = irow[k2]; wpi[k2] = pkh2(w.x, w.y);
        }
    }
    const float bias = bih[row] + bhh[row];   // used by half==0 at write
    const int bb = tid >> 7, jh = tid & 127;
    float creg = 0.f, hreg = 0.f;

    if (tid < 256) {
        h_h[bb][jh] = 0;
        y_h[bb][jh] = f2h(bf2f(ys[((size_t)(b0 + bb) * TT) * HH + jh]));
    }
    __syncthreads();

    for (int t = 0; t < TT; t++) {
        u16 ynext = 0;
        if (tid < 256 && t + 1 < TT)
            ynext = ys[((size_t)(b0 + bb) * TT + (t + 1)) * HH + jh];

        float a0 = 0.f, a1 = 0.f;
#pragma unroll
        for (int q = 0; q < 8; q++) {
            uint4 hq0 = *reinterpret_cast<const uint4*>(
                reinterpret_cast<const char*>(h_h[0]) + base * 2 + q * 16);
            uint4 hq1 = *reinterpret_cast<const uint4*>(
                reinterpret_cast<const char*>(h_h[1]) + base * 2 + q * 16);
            uint4 yq0 = *reinterpret_cast<const uint4*>(
                reinterpret_cast<const char*>(y_h[0]) + base * 2 + q * 16);
            uint4 yq1 = *reinterpret_cast<const uint4*>(
                reinterpret_cast<const char*>(y_h[1]) + base * 2 + q * 16);
            u32 h0 = wph[4 * q], h1 = wph[4 * q + 1], h2 = wph[4 * q + 2], h3 = wph[4 * q + 3];
            u32 i0 = wpi[4 * q], i1 = wpi[4 * q + 1], i2 = wpi[4 * q + 2], i3 = wpi[4 * q + 3];
            a0 = FDOT2(u2h(h0), u2h(hq0.x), a0);
            a0 = FDOT2(u2h(h1), u2h(hq0.y), a0);
            a0 = FDOT2(u2h(h2), u2h(hq0.z), a0);
            a0 = FDOT2(u2h(h3), u2h(hq0.w), a0);
            a0 = FDOT2(u2h(i0), u2h(yq0.x), a0);
            a0 = FDOT2(u2h(i1), u2h(yq0.y), a0);
            a0 = FDOT2(u2h(i2), u2h(yq0.z), a0);
            a0 = FDOT2(u2h(i3), u2h(yq0.w), a0);
            a1 = FDOT2(u2h(h0), u2h(hq1.x), a1);
            a1 = FDOT2(u2h(h1), u2h(hq1.y), a1);
            a1 = FDOT2(u2h(h2), u2h(hq1.z), a1);
            a1 = FDOT2(u2h(h3), u2h(hq1.w), a1);
            a1 = FDOT2(u2h(i0), u2h(yq1.x), a1);
            a1 = FDOT2(u2h(i1), u2h(yq1.y), a1);
            a1 = FDOT2(u2h(i2), u2h(yq1.z), a1);
            a1 = FDOT2(u2h(i3), u2h(yq1.w), a1);
        }
        a0 += __shfl_xor(a0, 1);
        a1 += __shfl_xor(a1, 1);
        if (half == 0) { z_s[0][row] = a0 + bias; z_s[1][row] = a1 + bias; }
        __syncthreads();

        if (tid < 256) {
            float zi = z_s[bb][jh], zf = z_s[bb][HH + jh], zg = z_s[bb][2 * HH + jh], zo = z_s[bb][3 * HH + jh];
            float c = sigm(zf) * creg + sigm(zi) * tanhf_(zg);
            float h = sigm(zo) * tanhf_(c);
            creg = c; hreg = h;
            h_h[bb][jh] = f2h(h);
            if (write_ys) ys[((size_t)(b0 + bb) * TT + t) * HH + jh] = f2bf(h);
            if (t + 1 < TT) y_h[bb][jh] = f2h(bf2f(ynext));
        }
        __syncthreads();
    }
    if (tid < 256) {
        hst[(size_t)(b0 + bb) * HH + jh] = hreg;
        cst[(size_t)(b0 + bb) * HH + jh] = creg;
    }
}

// ---------------------------------------------------------------------------
// Pack (unchanged — layout keyed to tid/p/m only, independent of batch/blk):
// o = ((m*4+p)*1024 + t)*8 + u ; row = p*128 + (t>>3); col = (t&7)*16 + 2u.
// ---------------------------------------------------------------------------
__global__ void __launch_bounds__(256) k_pack(
    const float* __restrict__ w0h, const float* __restrict__ w1i,
    const float* __restrict__ w1h, const float* __restrict__ w2i,
    const float* __restrict__ w2h, u32* __restrict__ wpk)
{
    int o = blockIdx.x * 256 + threadIdx.x;      // 0 .. 163839
    int m = o >> 15;            // 32768 u32 per matrix
    int rem = o & 32767;
    int p = rem >> 13;          // 8192 u32 per gate-block
    int rem2 = rem & 8191;
    int t = rem2 >> 3;          // thread 0..1023
    int u = rem2 & 7;           // u32 within thread's 2 uint4
    int row = p * 128 + (t >> 3);
    int col = (t & 7) * 16 + 2 * u;
    const float* src = (m == 0) ? w0h : (m == 1) ? w1i : (m == 2) ? w1h : (m == 3) ? w2i : w2h;
    float v0 = src[row * 128 + col], v1 = src[row * 128 + col + 1];
    wpk[o] = pkh2(v0, v1);
}

// ---------------------------------------------------------------------------
// Decoder: 50 steps x 3 layers. 1024 thr, **2 batch**, grid **256** — round 10
// ran grid 128 on 256 CUs (Occupancy 23%, half the machine idle; VALUBusy 14%
// => latency-bound, not BW: L2 demand 3.2 TB/s of 34.5). Full-CU grid is the
// 2x lever. Per-p next-weight prefetch (+16 regs in flight, VGPR ~80 < 128)
// shortens each phase's load->use chain.
// ---------------------------------------------------------------------------
__global__ void __launch_bounds__(1024) k_decode(
    const float* __restrict__ x,
    const float* __restrict__ w0i,
    const float* __restrict__ b0i, const float* __restrict__ b0h,
    const float* __restrict__ b1i, const float* __restrict__ b1h,
    const float* __restrict__ b2i, const float* __restrict__ b2h,
    const float* __restrict__ fcw, const float* __restrict__ fcb,
    const float* __restrict__ hst, const float* __restrict__ cst,
    const uint4* __restrict__ wpk,
    float* __restrict__ out)
{
    const int tid = threadIdx.x;
    const int b0 = blockIdx.x * 2;
    const int r = tid >> 3;        // output row slot 0..127
    const int g = tid & 7;         // 16-col group
    __shared__ __align__(16) u16  h_h[3][2][HH];     // f16 hidden states
    __shared__ __align__(16) float h2f_s[2][HH];     // f32 copy of layer-2 h (fc)
    __shared__ __align__(16) float z_s[2][G4];
    __shared__ __align__(16) float in0_s[2][4];
    __shared__ __align__(16) float fcw_s[HH];
    __shared__ __align__(16) float bs_lds[3][G4];    // bih+bhh per layer
    __shared__ __align__(16) float wi0_lds[G4][4];   // layer-0 wih rows

    const int bb = tid >> 7, jh = tid & 127;         // eltwise roles (tid<256)
    float c0 = 0.f, c1 = 0.f, c2 = 0.f;
    if (tid < 256) {
        c0 = cst[((size_t)0 * BB + b0 + bb) * HH + jh];
        c1 = cst[((size_t)1 * BB + b0 + bb) * HH + jh];
        c2 = cst[((size_t)2 * BB + b0 + bb) * HH + jh];
        h_h[0][bb][jh] = f2h(hst[((size_t)0 * BB + b0 + bb) * HH + jh]);
        h_h[1][bb][jh] = f2h(hst[((size_t)1 * BB + b0 + bb) * HH + jh]);
        h_h[2][bb][jh] = f2h(hst[((size_t)2 * BB + b0 + bb) * HH + jh]);
    }
    if (tid < 512) {
        bs_lds[0][tid] = b0i[tid] + b0h[tid];
        bs_lds[1][tid] = b1i[tid] + b1h[tid];
        bs_lds[2][tid] = b2i[tid] + b2h[tid];
        float4 wv = reinterpret_cast<const float4*>(w0i)[tid];
        wi0_lds[tid][0] = wv.x; wi0_lds[tid][1] = wv.y;
        wi0_lds[tid][2] = wv.z; wi0_lds[tid][3] = wv.w;
    }
    if (tid < HH) fcw_s[tid] = fcw[tid];
    if (tid < 8) in0_s[tid >> 2][tid & 3] = x[(size_t)(b0 + (tid >> 2)) * TT * 4 + (size_t)(TT - 1) * 4 + (tid & 3)];
    const float fcbv = fcb[0];
    __syncthreads();

#define VEC_CHUNK(l, b, q) (*reinterpret_cast<const uint4*>( \
        reinterpret_cast<const char*>(&h_h[l][b][0]) + g * 32 + (q) * 16))

    for (int s = 0; s < NPRED; s++) {
        // ================= layer 0: z = w0i*in0 + w0h*h0 =================
        {
            const uint4* w0c = wpk + (((0 * 4 + 0) * 1024 + tid) << 1);
            uint4 wA0 = w0c[0], wA1 = w0c[1];
#pragma unroll
            for (int p = 0; p < 4; p++) {
                uint4 wB0, wB1;
                if (p < 3) { wB0 = w0c[(p + 1) * 2048]; wB1 = w0c[(p + 1) * 2048 + 1]; }
                float a[2] = {0.f, 0.f};
#pragma unroll
                for (int b = 0; b < 2; b++) {
                    uint4 v0 = VEC_CHUNK(0, b, 0);
                    uint4 v1 = VEC_CHUNK(0, b, 1);
                    a[b] = FDOT2(u2h(wA0.x), u2h(v0.x), a[b]);
                    a[b] = FDOT2(u2h(wA0.y), u2h(v0.y), a[b]);
                    a[b] = FDOT2(u2h(wA0.z), u2h(v0.z), a[b]);
                    a[b] = FDOT2(u2h(wA0.w), u2h(v0.w), a[b]);
                    a[b] = FDOT2(u2h(wA1.x), u2h(v1.x), a[b]);
                    a[b] = FDOT2(u2h(wA1.y), u2h(v1.y), a[b]);
                    a[b] = FDOT2(u2h(wA1.z), u2h(v1.z), a[b]);
                    a[b] = FDOT2(u2h(wA1.w), u2h(v1.w), a[b]);
                }
#pragma unroll
                for (int b = 0; b < 2; b++) {
                    a[b] += __shfl_xor(a[b], 1);
                    a[b] += __shfl_xor(a[b], 2);
                    a[b] += __shfl_xor(a[b], 4);
                }
                if (g == 0) {
                    int row = p * 128 + r;
                    float w0 = wi0_lds[row][0], w1 = wi0_lds[row][1];
                    float w2 = wi0_lds[row][2], w3 = wi0_lds[row][3];
                    float bs = bs_lds[0][row];
#pragma unroll
                    for (int b = 0; b < 2; b++) {
                        float wi = w0 * in0_s[b][0] + w1 * in0_s[b][1]
                                 + w2 * in0_s[b][2] + w3 * in0_s[b][3];
                        z_s[b][row] = a[b] + bs + wi;
                    }
                }
                wA0 = wB0; wA1 = wB1;
            }
        }
        __syncthreads();
        if (tid < 256) {
            float zi = z_s[bb][jh], zf = z_s[bb][HH + jh], zg = z_s[bb][2 * HH + jh], zo = z_s[bb][3 * HH + jh];
            c0 = sigm(zf) * c0 + sigm(zi) * tanhf_(zg);
            float h = sigm(zo) * tanhf_(c0);
            h_h[0][bb][jh] = f2h(h);
        }
        __syncthreads();
        // ================= layer 1: z = w1i*h0 + w1h*h1 =================
        {
            const uint4* wic = wpk + (((1 * 4 + 0) * 1024 + tid) << 1);
            const uint4* whc = wpk + (((2 * 4 + 0) * 1024 + tid) << 1);
            uint4 iA0 = wic[0], iA1 = wic[1], hA0 = whc[0], hA1 = whc[1];
#pragma unroll
            for (int p = 0; p < 4; p++) {
                uint4 iB0, iB1, hB0, hB1;
                if (p < 3) {
                    iB0 = wic[(p + 1) * 2048]; iB1 = wic[(p + 1) * 2048 + 1];
                    hB0 = whc[(p + 1) * 2048]; hB1 = whc[(p + 1) * 2048 + 1];
                }
                float a[2] = {0.f, 0.f};
#pragma unroll
                for (int b = 0; b < 2; b++) {
                    uint4 vi0 = VEC_CHUNK(0, b, 0);
                    uint4 vi1 = VEC_CHUNK(0, b, 1);
                    uint4 vh0 = VEC_CHUNK(1, b, 0);
                    uint4 vh1 = VEC_CHUNK(1, b, 1);
                    a[b] = FDOT2(u2h(iA0.x), u2h(vi0.x), a[b]);
                    a[b] = FDOT2(u2h(iA0.y), u2h(vi0.y), a[b]);
                    a[b] = FDOT2(u2h(iA0.z), u2h(vi0.z), a[b]);
                    a[b] = FDOT2(u2h(iA0.w), u2h(vi0.w), a[b]);
                    a[b] = FDOT2(u2h(iA1.x), u2h(vi1.x), a[b]);
                    a[b] = FDOT2(u2h(iA1.y), u2h(vi1.y), a[b]);
                    a[b] = FDOT2(u2h(iA1.z), u2h(vi1.z), a[b]);
                    a[b] = FDOT2(u2h(iA1.w), u2h(vi1.w), a[b]);
                    a[b] = FDOT2(u2h(hA0.x), u2h(vh0.x), a[b]);
                    a[b] = FDOT2(u2h(hA0.y), u2h(vh0.y), a[b]);
                    a[b] = FDOT2(u2h(hA0.z), u2h(vh0.z), a[b]);
                    a[b] = FDOT2(u2h(hA0.w), u2h(vh0.w), a[b]);
                    a[b] = FDOT2(u2h(hA1.x), u2h(vh1.x), a[b]);
                    a[b] = FDOT2(u2h(hA1.y), u2h(vh1.y), a[b]);
                    a[b] = FDOT2(u2h(hA1.z), u2h(vh1.z), a[b]);
                    a[b] = FDOT2(u2h(hA1.w), u2h(vh1.w), a[b]);
                }
#pragma unroll
                for (int b = 0; b < 2; b++) {
                    a[b] += __shfl_xor(a[b], 1);
                    a[b] += __shfl_xor(a[b], 2);
                    a[b] += __shfl_xor(a[b], 4);
                }
                if (g == 0) {
                    int row = p * 128 + r;
                    float bs = bs_lds[1][row];
#pragma unroll
                    for (int b = 0; b < 2; b++) z_s[b][row] = a[b] + bs;
                }
                iA0 = iB0; iA1 = iB1; hA0 = hB0; hA1 = hB1;
            }
        }
        __syncthreads();
        if (tid < 256) {
            float zi = z_s[bb][jh], zf = z_s[bb][HH + jh], zg = z_s[bb][2 * HH + jh], zo = z_s[bb][3 * HH + jh];
            c1 = sigm(zf) * c1 + sigm(zi) * tanhf_(zg);
            float h = sigm(zo) * tanhf_(c1);
            h_h[1][bb][jh] = f2h(h);
        }
        __syncthreads();
        // ================= layer 2: z = w2i*h1 + w2h*h2 =================
        {
            const uint4* wic = wpk + (((3 * 4 + 0) * 1024 + tid) << 1);
            const uint4* whc = wpk + (((4 * 4 + 0) * 1024 + tid) << 1);
            uint4 iA0 = wic[0], iA1 = wic[1], hA0 = whc[0], hA1 = whc[1];
#pragma unroll
            for (int p = 0; p < 4; p++) {
                uint4 iB0, iB1, hB0, hB1;
                if (p < 3) {
                    iB0 = wic[(p + 1) * 2048]; iB1 = wic[(p + 1) * 2048 + 1];
                    hB0 = whc[(p + 1) * 2048]; hB1 = whc[(p + 1) * 2048 + 1];
                }
                float a[2] = {0.f, 0.f};
#pragma unroll
                for (int b = 0; b < 2; b++) {
                    uint4 vi0 = VEC_CHUNK(1, b, 0);
                    uint4 vi1 = VEC_CHUNK(1, b, 1);
                    uint4 vh0 = VEC_CHUNK(2, b, 0);
                    uint4 vh1 = VEC_CHUNK(2, b, 1);
                    a[b] = FDOT2(u2h(iA0.x), u2h(vi0.x), a[b]);
                    a[b] = FDOT2(u2h(iA0.y), u2h(vi0.y), a[b]);
                    a[b] = FDOT2(u2h(iA0.z), u2h(vi0.z), a[b]);
                    a[b] = FDOT2(u2h(iA0.w), u2h(vi0.w), a[b]);
                    a[b] = FDOT2(u2h(iA1.x), u2h(vi1.x), a[b]);
                    a[b] = FDOT2(u2h(iA1.y), u2h(vi1.y), a[b]);
                    a[b] = FDOT2(u2h(iA1.z), u2h(vi1.z), a[b]);
                    a[b] = FDOT2(u2h(iA1.w), u2h(vi1.w), a[b]);
                    a[b] = FDOT2(u2h(hA0.x), u2h(vh0.x), a[b]);
                    a[b] = FDOT2(u2h(hA0.y), u2h(vh0.y), a[b]);
                    a[b] = FDOT2(u2h(hA0.z), u2h(vh0.z), a[b]);
                    a[b] = FDOT2(u2h(hA0.w), u2h(vh0.w), a[b]);
                    a[b] = FDOT2(u2h(hA1.x), u2h(vh1.x), a[b]);
                    a[b] = FDOT2(u2h(hA1.y), u2h(vh1.y), a[b]);
                    a[b] = FDOT2(u2h(hA1.z), u2h(vh1.z), a[b]);
                    a[b] = FDOT2(u2h(hA1.w), u2h(vh1.w), a[b]);
                }
#pragma unroll
                for (int b = 0; b < 2; b++) {
                    a[b] += __shfl_xor(a[b], 1);
                    a[b] += __shfl_xor(a[b], 2);
                    a[b] += __shfl_xor(a[b], 4);
                }
                if (g == 0) {
                    int row = p * 128 + r;
                    float bs = bs_lds[2][row];
#pragma unroll
                    for (int b = 0; b < 2; b++) z_s[b][row] = a[b] + bs;
                }
                iA0 = iB0; iA1 = iB1; hA0 = hB0; hA1 = hB1;
            }
        }
        __syncthreads();
        if (tid < 256) {
            float zi = z_s[bb][jh], zf = z_s[bb][HH + jh], zg = z_s[bb][2 * HH + jh], zo = z_s[bb][3 * HH + jh];
            c2 = sigm(zf) * c2 + sigm(zi) * tanhf_(zg);
            float h = sigm(zo) * tanhf_(c2);
            h_h[2][bb][jh] = f2h(h);
            h2f_s[bb][jh] = h;
        }
        __syncthreads();
        // ----- fc + feedback -----
        if (tid < 128) {
            const int w = tid >> 6, lane = tid & 63;
            float p = h2f_s[w][lane] * fcw_s[lane] + h2f_s[w][lane + 64] * fcw_s[lane + 64];
#pragma unroll
            for (int off = 32; off > 0; off >>= 1) p += __shfl_down(p, off);
            if (lane == 0) {
                float pr = p + fcbv;
                out[(size_t)(b0 + w) * NPRED + s] = pr;
                in0_s[w][0] = pr;
            }
        } else if (tid < 136) {
            int q = tid - 128;            // 0..7
            int b = q >> 2, k = q & 3;
            if (k > 0) in0_s[b][k] = 0.f; // zeros_feat
        }
        __syncthreads();
    }
#undef VEC_CHUNK
}

extern "C" void kernel_launch(void* const* d_in, const int* in_sizes, int n_in,
                              void* d_out, int out_size, void* d_ws, size_t ws_size,
                              hipStream_t stream)
{
    const float* x = (const float*)d_in[0];
    const float* e0_wih = (const float*)d_in[1];
    const float* e0_whh = (const float*)d_in[2];
    const float* e0_bih = (const float*)d_in[3];
    const float* e0_bhh = (const float*)d_in[4];
    const float* e1_wih = (const float*)d_in[5];
    const float* e1_whh = (const float*)d_in[6];
    const float* e1_bih = (const float*)d_in[7];
    const float* e1_bhh = (const float*)d_in[8];
    const float* e2_wih = (const float*)d_in[9];
    const float* e2_whh = (const float*)d_in[10];
    const float* e2_bih = (const float*)d_in[11];
    const float* e2_bhh = (const float*)d_in[12];
    const float* d0_wih = (const float*)d_in[13];
    const float* d0_whh = (const float*)d_in[14];
    const float* d0_bih = (const float*)d_in[15];
    const float* d0_bhh = (const float*)d_in[16];
    const float* d1_wih = (const float*)d_in[17];
    const float* d1_whh = (const float*)d_in[18];
    const float* d1_bih = (const float*)d_in[19];
    const float* d1_bhh = (const float*)d_in[20];
    const float* d2_wih = (const float*)d_in[21];
    const float* d2_whh = (const float*)d_in[22];
    const float* d2_bih = (const float*)d_in[23];
    const float* d2_bhh = (const float*)d_in[24];
    const float* fc_w = (const float*)d_in[25];
    const float* fc_b = (const float*)d_in[26];

    // workspace layout
    u16* ys = (u16*)d_ws;                                   // B*T*H bf16 = 33.5 MB
    size_t ys_bytes = (size_t)BB * TT * HH * sizeof(u16);
    float* hst = (float*)((char*)d_ws + ys_bytes);          // 3*B*H f32
    float* cst = hst + (size_t)3 * BB * HH;                 // 3*B*H f32
    u32* wpk = (u32*)(cst + (size_t)3 * BB * HH);           // 163840 u32 = 640 KB
    const size_t BH = (size_t)BB * HH;

    k_pack<<<dim3(640), dim3(256), 0, stream>>>(d0_whh, d1_wih, d1_whh, d2_wih, d2_whh, wpk);
    k_scan0<<<dim3(256), dim3(1024), 0, stream>>>(x, e0_wih, e0_whh, e0_bih, e0_bhh,
                                                  ys, hst, cst);
    k_scanL<<<dim3(256), dim3(1024), 0, stream>>>(e1_wih, e1_whh, e1_bih, e1_bhh,
                                                  ys, 1, hst + BH, cst + BH);
    k_scanL<<<dim3(256), dim3(1024), 0, stream>>>(e2_wih, e2_whh, e2_bih, e2_bhh,
                                                  ys, 0, hst + 2 * BH, cst + 2 * BH);
    k_decode<<<dim3(256), dim3(1024), 0, stream>>>(
        x, d0_wih, d0_bih, d0_bhh, d1_bih, d1_bhh, d2_bih, d2_bhh,
        fc_w, fc_b, hst, cst, (const uint4*)wpk, (float*)d_out);
}